// Round 1
// baseline (613.430 us; speedup 1.0000x reference)
//
#include <hip/hip_runtime.h>
#include <stdint.h>
#include <stddef.h>

typedef __attribute__((ext_vector_type(8))) short bf16x8;
typedef __attribute__((ext_vector_type(4))) float f32x4;

__device__ __forceinline__ unsigned short f2bf(float f) {
  union { float f; unsigned int u; } v; v.f = f;
  unsigned int u = v.u;
  u += 0x7fffu + ((u >> 16) & 1u);   // round-to-nearest-even
  return (unsigned short)(u >> 16);
}
__device__ __forceinline__ float bf2f(unsigned short s) {
  union { unsigned int u; float f; } v; v.u = ((unsigned int)s) << 16;
  return v.f;
}

// ---------------------------------------------------------------------------
// prep: convert weights / rel tables to bf16 layouts in workspace
//   wqkv_b [1536][512], wproj_b [512][512], relk_b [256][64] (rows>=225 zero),
//   relvT_b [64][256] (rel_v transposed, cols>=225 zero)
// ---------------------------------------------------------------------------
__global__ void prep_kernel(const float* __restrict__ wqkv,
                            const float* __restrict__ wproj,
                            const float* __restrict__ relk,
                            const float* __restrict__ relv,
                            short* __restrict__ wqkv_b,
                            short* __restrict__ wproj_b,
                            short* __restrict__ relk_b,
                            short* __restrict__ relvT_b) {
  int tid = blockIdx.x * 256 + threadIdx.x;
  if (tid < 1536 * 512) wqkv_b[tid] = (short)f2bf(wqkv[tid]);
  if (tid < 512 * 512) wproj_b[tid] = (short)f2bf(wproj[tid]);
  if (tid < 256 * 64) {
    int nb = tid >> 6;
    relk_b[tid] = (nb < 225) ? (short)f2bf(relk[tid]) : (short)0;
  }
  if (tid < 64 * 256) {
    int d = tid >> 8, nb = tid & 255;
    relvT_b[tid] = (nb < 225) ? (short)f2bf(relv[nb * 64 + d]) : (short)0;
  }
}

// ---------------------------------------------------------------------------
// fused qkv-projection + relative attention, one block per batch b.
// 512 threads = 8 waves in a 2(m) x 4(n) grid.
// ---------------------------------------------------------------------------
__global__ __launch_bounds__(512, 2)
void fused_qkv_attn(const float* __restrict__ x,
                    const short* __restrict__ wqkv,
                    const short* __restrict__ relk,
                    const short* __restrict__ relvT,
                    short* __restrict__ aout) {
  __shared__ __align__(16) short x_s[64 * 512];    // 64 KB, swizzled
  __shared__ __align__(16) short q_s[64 * 64];     // 8 KB, swizzled  [t][d]
  __shared__ __align__(16) short k_s[64 * 64];     // 8 KB, swizzled  [t][d]
  __shared__ __align__(16) short vT_s[64 * 64];    // 8 KB, swizzled  [d][t]
  __shared__ __align__(16) short p_s[64 * 256];    // 32 KB, swizzled: Srel then P
  __shared__ __align__(16) float logit_s[64 * 64]; // 16 KB plain f32
  __shared__ __align__(16) short attn_s[64 * 64];  // 8 KB, swizzled  [i][j]

  const int tid = threadIdx.x;
  const int lane = tid & 63;
  const int wm = (tid >> 6) >> 2;  // 0..1
  const int wn = (tid >> 6) & 3;   // 0..3
  const int l15 = lane & 15;
  const int l4 = lane >> 4;        // 0..3
  const int b = blockIdx.x;

  char* xs = (char*)x_s;
  char* qs = (char*)q_s;
  char* ks = (char*)k_s;
  char* vs = (char*)vT_s;
  char* ps = (char*)p_s;
  char* as = (char*)attn_s;

  // ---- phase 0: x[b] fp32 -> bf16 into swizzled LDS ----
  {
    const int row = tid >> 3;
    const int seg = tid & 7;
    const float* src = x + ((size_t)b * 64 + row) * 512 + seg * 64;
    char* dst = xs + row * 1024;
    const int swz = (row & 7) << 4;
#pragma unroll
    for (int i = 0; i < 8; ++i) {
      float4 f0 = *(const float4*)(src + i * 8);
      float4 f1 = *(const float4*)(src + i * 8 + 4);
      uint4 w;
      w.x = f2bf(f0.x) | ((unsigned)f2bf(f0.y) << 16);
      w.y = f2bf(f0.z) | ((unsigned)f2bf(f0.w) << 16);
      w.z = f2bf(f1.x) | ((unsigned)f2bf(f1.y) << 16);
      w.w = f2bf(f1.z) | ((unsigned)f2bf(f1.w) << 16);
      const int col2 = (seg * 64 + i * 8) * 2;
      *(uint4*)(dst + (col2 ^ swz)) = w;
    }
  }
  __syncthreads();

  const f32x4 fz = {0.f, 0.f, 0.f, 0.f};

  for (int h = 0; h < 8; ++h) {
    // ===== phase 1: q,k,v = x @ w_slice^T (M=64, N=192, K=512) =====
    f32x4 acc1[2][3];
#pragma unroll
    for (int mi = 0; mi < 2; ++mi)
#pragma unroll
      for (int r = 0; r < 3; ++r) acc1[mi][r] = fz;

#pragma unroll 2
    for (int kk = 0; kk < 16; ++kk) {
      bf16x8 av[2], bv[3];
#pragma unroll
      for (int mi = 0; mi < 2; ++mi) {
        const int row = 16 * (2 * wm + mi) + l15;
        const int col2 = (32 * kk + 8 * l4) * 2;
        av[mi] = *(const bf16x8*)(xs + row * 1024 + (col2 ^ ((row & 7) << 4)));
      }
#pragma unroll
      for (int r = 0; r < 3; ++r) {
        const int nt = 3 * wn + r;  // 0..11 -> q:0-3 k:4-7 v:8-11
        const int nrow = (nt >> 2) * 512 + h * 64 + (nt & 3) * 16 + l15;
        bv[r] = *(const bf16x8*)(wqkv + (size_t)nrow * 512 + 32 * kk + 8 * l4);
      }
#pragma unroll
      for (int mi = 0; mi < 2; ++mi)
#pragma unroll
        for (int r = 0; r < 3; ++r)
          acc1[mi][r] = __builtin_amdgcn_mfma_f32_16x16x32_bf16(av[mi], bv[r], acc1[mi][r], 0, 0, 0);
    }
    // store fragments: q,k row-major [t][d]; v transposed [d][t]
#pragma unroll
    for (int mi = 0; mi < 2; ++mi) {
      const int r0 = 16 * (2 * wm + mi) + 4 * l4;
#pragma unroll
      for (int r = 0; r < 3; ++r) {
        const int nt = 3 * wn + r;
        const int three = nt >> 2;
        const int col = (nt & 3) * 16 + l15;  // d within head
        if (three == 2) {
          uint2 w;
          w.x = f2bf(acc1[mi][r][0]) | ((unsigned)f2bf(acc1[mi][r][1]) << 16);
          w.y = f2bf(acc1[mi][r][2]) | ((unsigned)f2bf(acc1[mi][r][3]) << 16);
          *(uint2*)(vs + col * 128 + ((r0 * 2) ^ ((col & 7) << 4))) = w;
        } else {
          char* base = (three == 0) ? qs : ks;
#pragma unroll
          for (int jj = 0; jj < 4; ++jj) {
            const int row = r0 + jj;
            *(unsigned short*)(base + row * 128 + ((col * 2) ^ ((row & 7) << 4))) =
                f2bf(acc1[mi][r][jj]);
          }
        }
      }
    }
    __syncthreads();

    // ===== phase 2: [ q@k^T | q@rel_k^T ]  (M=64, N=64+256, K=64) =====
    f32x4 acc2[2][5];
#pragma unroll
    for (int mi = 0; mi < 2; ++mi)
#pragma unroll
      for (int r = 0; r < 5; ++r) acc2[mi][r] = fz;

#pragma unroll
    for (int kk = 0; kk < 2; ++kk) {
      bf16x8 av[2], bv[5];
      const int col2 = (32 * kk + 8 * l4) * 2;
#pragma unroll
      for (int mi = 0; mi < 2; ++mi) {
        const int row = 16 * (2 * wm + mi) + l15;
        av[mi] = *(const bf16x8*)(qs + row * 128 + (col2 ^ ((row & 7) << 4)));
      }
#pragma unroll
      for (int r = 0; r < 5; ++r) {
        const int nt = 5 * wn + r;  // 0..19; 0-3 = j tiles, 4-19 = bucket tiles
        if (nt < 4) {
          const int row = 16 * nt + l15;
          bv[r] = *(const bf16x8*)(ks + row * 128 + (col2 ^ ((row & 7) << 4)));
        } else {
          const int nb = (nt - 4) * 16 + l15;
          bv[r] = *(const bf16x8*)(relk + nb * 64 + 32 * kk + 8 * l4);
        }
      }
#pragma unroll
      for (int mi = 0; mi < 2; ++mi)
#pragma unroll
        for (int r = 0; r < 5; ++r)
          acc2[mi][r] = __builtin_amdgcn_mfma_f32_16x16x32_bf16(av[mi], bv[r], acc2[mi][r], 0, 0, 0);
    }
#pragma unroll
    for (int mi = 0; mi < 2; ++mi) {
      const int r0 = 16 * (2 * wm + mi) + 4 * l4;
#pragma unroll
      for (int r = 0; r < 5; ++r) {
        const int nt = 5 * wn + r;
        if (nt < 4) {
          const int j0 = 16 * nt + l15;
#pragma unroll
          for (int jj = 0; jj < 4; ++jj) logit_s[(r0 + jj) * 64 + j0] = acc2[mi][r][jj];
        } else {
          const int nb = (nt - 4) * 16 + l15;
#pragma unroll
          for (int jj = 0; jj < 4; ++jj) {
            const int row = r0 + jj;
            *(unsigned short*)(ps + row * 512 + ((nb * 2) ^ ((row & 7) << 4))) =
                f2bf(acc2[mi][r][jj]);
          }
        }
      }
    }
    __syncthreads();

    // ===== phase 3: softmax (8 threads per row) =====
    const int i = tid >> 3;
    const int g = tid & 7;
    float pv[8];
    int nbv[8];
    {
      const float* lr = logit_s + i * 64 + g * 8;
      const int ri = i >> 3, fi = i & 7;
      float mx = -1e30f;
#pragma unroll
      for (int jj = 0; jj < 8; ++jj) {
        const int j = g * 8 + jj;
        const int nb = ((j >> 3) - ri + 7) * 15 + ((j & 7) - fi + 7);
        nbv[jj] = nb;
        const float sr = bf2f(*(const unsigned short*)(ps + i * 512 + ((nb * 2) ^ ((i & 7) << 4))));
        const float lv = (lr[jj] + sr) * 0.125f;
        pv[jj] = lv;
        mx = fmaxf(mx, lv);
      }
      mx = fmaxf(mx, __shfl_xor(mx, 1));
      mx = fmaxf(mx, __shfl_xor(mx, 2));
      mx = fmaxf(mx, __shfl_xor(mx, 4));
      float sum = 0.f;
#pragma unroll
      for (int jj = 0; jj < 8; ++jj) {
        pv[jj] = __expf(pv[jj] - mx);
        sum += pv[jj];
      }
      sum += __shfl_xor(sum, 1);
      sum += __shfl_xor(sum, 2);
      sum += __shfl_xor(sum, 4);
      const float rs = 1.0f / sum;
      unsigned wv0[4];
#pragma unroll
      for (int k2 = 0; k2 < 4; ++k2) {
        float a0 = pv[2 * k2] * rs, a1 = pv[2 * k2 + 1] * rs;
        pv[2 * k2] = a0;
        pv[2 * k2 + 1] = a1;
        wv0[k2] = f2bf(a0) | ((unsigned)f2bf(a1) << 16);
      }
      uint4 w;
      w.x = wv0[0]; w.y = wv0[1]; w.z = wv0[2]; w.w = wv0[3];
      *(uint4*)(as + i * 128 + ((g * 16) ^ ((i & 7) << 4))) = w;
    }
    __syncthreads();
    {  // zero P (reuse of Srel region)
      const uint4 uz = {0u, 0u, 0u, 0u};
#pragma unroll
      for (int c = 0; c < 4; ++c) *(uint4*)(ps + tid * 64 + c * 16) = uz;
    }
    __syncthreads();
#pragma unroll
    for (int jj = 0; jj < 8; ++jj)  // scatter attn -> P (injective per row)
      *(unsigned short*)(ps + i * 512 + ((nbv[jj] * 2) ^ ((i & 7) << 4))) = f2bf(pv[jj]);
    __syncthreads();

    // ===== phase 4: out = [attn|P] @ [v ; rel_v]  (M=64, N=64, K=320) =====
    f32x4 acc3[2];
    acc3[0] = fz;
    acc3[1] = fz;
#pragma unroll
    for (int kk = 0; kk < 10; ++kk) {
      bf16x8 av[2], bv;
      if (kk < 2) {
        const int c2 = (32 * kk + 8 * l4) * 2;
#pragma unroll
        for (int mi = 0; mi < 2; ++mi) {
          const int row = 16 * (2 * wm + mi) + l15;
          av[mi] = *(const bf16x8*)(as + row * 128 + (c2 ^ ((row & 7) << 4)));
        }
        const int dr = 16 * wn + l15;
        bv = *(const bf16x8*)(vs + dr * 128 + (c2 ^ ((dr & 7) << 4)));
      } else {
        const int c2 = (32 * (kk - 2) + 8 * l4) * 2;
#pragma unroll
        for (int mi = 0; mi < 2; ++mi) {
          const int row = 16 * (2 * wm + mi) + l15;
          av[mi] = *(const bf16x8*)(ps + row * 512 + (c2 ^ ((row & 7) << 4)));
        }
        const int dr = 16 * wn + l15;
        bv = *(const bf16x8*)(relvT + dr * 256 + 32 * (kk - 2) + 8 * l4);
      }
      acc3[0] = __builtin_amdgcn_mfma_f32_16x16x32_bf16(av[0], bv, acc3[0], 0, 0, 0);
      acc3[1] = __builtin_amdgcn_mfma_f32_16x16x32_bf16(av[1], bv, acc3[1], 0, 0, 0);
    }
#pragma unroll
    for (int mi = 0; mi < 2; ++mi) {
      const int r0 = 16 * (2 * wm + mi) + 4 * l4;
      const int col = h * 64 + 16 * wn + l15;
#pragma unroll
      for (int jj = 0; jj < 4; ++jj)
        aout[((size_t)b * 64 + r0 + jj) * 512 + col] = (short)f2bf(acc3[mi][jj]);
    }
    __syncthreads();
  }
}

// ---------------------------------------------------------------------------
// proj: out = aout(bf16) @ w_proj^T + b_proj, M=65536 N=512 K=512, fp32 out
// 128x128 tile, BK=64, reg-staged swizzled LDS, 4 waves (2x2), 64x64 each
// ---------------------------------------------------------------------------
__global__ __launch_bounds__(256)
void proj_kernel(const short* __restrict__ aout, const short* __restrict__ wproj,
                 const float* __restrict__ bproj, float* __restrict__ out) {
  __shared__ __align__(16) short As[128 * 64];  // 16 KB swizzled
  __shared__ __align__(16) short Bs[128 * 64];  // 16 KB swizzled
  const int tid = threadIdx.x;
  const int lane = tid & 63;
  const int wave = tid >> 6;
  const int wm = wave >> 1, wn = wave & 1;
  const int l15 = lane & 15, l4 = lane >> 4;
  const int bm = blockIdx.x, bn = blockIdx.y;
  char* as_ = (char*)As;
  char* bs_ = (char*)Bs;

  const f32x4 fz = {0.f, 0.f, 0.f, 0.f};
  f32x4 acc[4][4];
#pragma unroll
  for (int mt = 0; mt < 4; ++mt)
#pragma unroll
    for (int nt = 0; nt < 4; ++nt) acc[mt][nt] = fz;

  for (int kk = 0; kk < 8; ++kk) {
#pragma unroll
    for (int c = 0; c < 4; ++c) {
      const int off = (tid * 4 + c) * 16;  // linear (already-swizzled) LDS byte offset
      const int row = off >> 7;
      const int lg = ((off >> 4) & 7) ^ (row & 7);  // logical 16B granule
      const short* gA = aout + ((size_t)(bm * 128 + row)) * 512 + kk * 64 + lg * 8;
      const short* gB = wproj + ((size_t)(bn * 128 + row)) * 512 + kk * 64 + lg * 8;
      *(uint4*)(as_ + off) = *(const uint4*)gA;
      *(uint4*)(bs_ + off) = *(const uint4*)gB;
    }
    __syncthreads();
#pragma unroll
    for (int ki = 0; ki < 2; ++ki) {
      bf16x8 af[4], bq[4];
#pragma unroll
      for (int mt = 0; mt < 4; ++mt) {
        const int row = 64 * wm + 16 * mt + l15;
        const int col2 = 64 * ki + 16 * l4;
        af[mt] = *(const bf16x8*)(as_ + row * 128 + (col2 ^ ((row & 7) << 4)));
      }
#pragma unroll
      for (int nt = 0; nt < 4; ++nt) {
        const int row = 64 * wn + 16 * nt + l15;
        const int col2 = 64 * ki + 16 * l4;
        bq[nt] = *(const bf16x8*)(bs_ + row * 128 + (col2 ^ ((row & 7) << 4)));
      }
#pragma unroll
      for (int mt = 0; mt < 4; ++mt)
#pragma unroll
        for (int nt = 0; nt < 4; ++nt)
          acc[mt][nt] = __builtin_amdgcn_mfma_f32_16x16x32_bf16(af[mt], bq[nt], acc[mt][nt], 0, 0, 0);
    }
    __syncthreads();
  }
#pragma unroll
  for (int nt = 0; nt < 4; ++nt) {
    const int col = bn * 128 + 64 * wn + 16 * nt + l15;
    const float bias = bproj[col];
#pragma unroll
    for (int mt = 0; mt < 4; ++mt) {
      const int r0 = bm * 128 + 64 * wm + 16 * mt + 4 * l4;
#pragma unroll
      for (int jj = 0; jj < 4; ++jj)
        out[(size_t)(r0 + jj) * 512 + col] = acc[mt][nt][jj] + bias;
    }
  }
}

// ---------------------------------------------------------------------------
extern "C" void kernel_launch(void* const* d_in, const int* in_sizes, int n_in,
                              void* d_out, int out_size, void* d_ws, size_t ws_size,
                              hipStream_t stream) {
  const float* x = (const float*)d_in[0];
  const float* wqkv = (const float*)d_in[1];
  const float* wproj = (const float*)d_in[2];
  const float* bproj = (const float*)d_in[3];
  const float* relk = (const float*)d_in[4];
  const float* relv = (const float*)d_in[5];
  float* out = (float*)d_out;

  char* ws = (char*)d_ws;
  short* aout = (short*)(ws);                    // 65536*512*2 = 67108864 B
  short* wqkv_b = (short*)(ws + 67108864);       // 1536*512*2  = 1572864 B
  short* wproj_b = (short*)(ws + 68681728);      // 512*512*2   = 524288 B
  short* relk_b = (short*)(ws + 69206016);       // 256*64*2    = 32768 B
  short* relvT_b = (short*)(ws + 69238784);      // 64*256*2    = 32768 B

  prep_kernel<<<dim3(3072), dim3(256), 0, stream>>>(wqkv, wproj, relk, relv, wqkv_b,
                                                    wproj_b, relk_b, relvT_b);
  fused_qkv_attn<<<dim3(1024), dim3(512), 0, stream>>>(x, wqkv_b, relk_b, relvT_b, aout);
  proj_kernel<<<dim3(512, 4), dim3(256), 0, stream>>>(aout, wproj_b, bproj, out);
}

// Round 2
// 609.184 us; speedup vs baseline: 1.0070x; 1.0070x over previous
//
#include <hip/hip_runtime.h>
#include <stdint.h>
#include <stddef.h>

typedef __attribute__((ext_vector_type(8))) short bf16x8;
typedef __attribute__((ext_vector_type(4))) float f32x4;

__device__ __forceinline__ unsigned short f2bf(float f) {
  union { float f; unsigned int u; } v; v.f = f;
  unsigned int u = v.u;
  u += 0x7fffu + ((u >> 16) & 1u);   // round-to-nearest-even
  return (unsigned short)(u >> 16);
}
__device__ __forceinline__ float bf2f(unsigned short s) {
  union { unsigned int u; float f; } v; v.u = ((unsigned int)s) << 16;
  return v.f;
}

// ---------------------------------------------------------------------------
// prep: weights / rel tables to bf16 layouts in workspace
//   wqkv_b [1536][512], wproj_b [512][512], relk_b [256][64] (rows>=225 zero),
//   relvT_b [64][256] (rel_v transposed, cols>=225 zero)
// ---------------------------------------------------------------------------
__global__ void prep_kernel(const float* __restrict__ wqkv,
                            const float* __restrict__ wproj,
                            const float* __restrict__ relk,
                            const float* __restrict__ relv,
                            short* __restrict__ wqkv_b,
                            short* __restrict__ wproj_b,
                            short* __restrict__ relk_b,
                            short* __restrict__ relvT_b) {
  const int tid = blockIdx.x * 256 + threadIdx.x;  // 0..196607
  {  // wqkv: 786432 elems, 4/thread
    const int i4 = tid * 4;
    float4 f = *(const float4*)(wqkv + i4);
    uint2 w;
    w.x = f2bf(f.x) | ((unsigned)f2bf(f.y) << 16);
    w.y = f2bf(f.z) | ((unsigned)f2bf(f.w) << 16);
    *(uint2*)(wqkv_b + i4) = w;
  }
  if (tid < 65536) {  // wproj: 262144 elems
    const int i4 = tid * 4;
    float4 f = *(const float4*)(wproj + i4);
    uint2 w;
    w.x = f2bf(f.x) | ((unsigned)f2bf(f.y) << 16);
    w.y = f2bf(f.z) | ((unsigned)f2bf(f.w) << 16);
    *(uint2*)(wproj_b + i4) = w;
  }
  if (tid < 4096) {  // relk_b: 16384 elems
    const int i4 = tid * 4;
    const int nb = i4 >> 6;
    uint2 w = {0u, 0u};
    if (nb < 225) {
      float4 f = *(const float4*)(relk + i4);
      w.x = f2bf(f.x) | ((unsigned)f2bf(f.y) << 16);
      w.y = f2bf(f.z) | ((unsigned)f2bf(f.w) << 16);
    }
    *(uint2*)(relk_b + i4) = w;
  }
  if (tid < 4096) {  // relvT_b: 16384 elems, [d][nb]
    const int i4 = tid * 4;
    const int d = i4 >> 8;
    const int nb0 = i4 & 255;
    unsigned short s[4];
#pragma unroll
    for (int j = 0; j < 4; ++j) {
      const int nb = nb0 + j;
      s[j] = (nb < 225) ? f2bf(relv[nb * 64 + d]) : (unsigned short)0;
    }
    uint2 w;
    w.x = s[0] | ((unsigned)s[1] << 16);
    w.y = s[2] | ((unsigned)s[3] << 16);
    *(uint2*)(relvT_b + i4) = w;
  }
}

// ---------------------------------------------------------------------------
// QKV GEMM: M=65536 (b,t), N=1536 (three,h,d), K=512. A=x fp32 (inline->bf16),
// B=wqkv bf16. 128x128 tile, BK=64, 4 waves. Outputs:
//   q_g,k_g [bh][t][d]  (scalar stores),  vT_g [bh][d][t] (uint2 stores)
// XCD-swizzled so each XCD owns contiguous bm range (x read once from HBM).
// ---------------------------------------------------------------------------
__global__ __launch_bounds__(256)
void qkv_gemm(const float* __restrict__ x, const short* __restrict__ wqkv,
              short* __restrict__ q_g, short* __restrict__ k_g,
              short* __restrict__ vT_g) {
  __shared__ __align__(16) short As[128 * 64];
  __shared__ __align__(16) short Bs[128 * 64];
  const int tid = threadIdx.x;
  const int lane = tid & 63;
  const int l15 = lane & 15, l4 = lane >> 4;
  const int wave = tid >> 6;
  const int wm = wave >> 1, wn = wave & 1;
  const int bid = blockIdx.x;                 // 6144 blocks
  const int wg = (bid & 7) * 768 + (bid >> 3);
  const int bn = wg % 12;
  const int bm = wg / 12;
  char* as_ = (char*)As;
  char* bs_ = (char*)Bs;

  const f32x4 fz = {0.f, 0.f, 0.f, 0.f};
  f32x4 acc[4][4];
#pragma unroll
  for (int mt = 0; mt < 4; ++mt)
#pragma unroll
    for (int nt = 0; nt < 4; ++nt) acc[mt][nt] = fz;

#pragma unroll 1
  for (int kk = 0; kk < 8; ++kk) {
    uint4 astage[4], bstage[4];
#pragma unroll
    for (int r = 0; r < 4; ++r) {
      const int idx = tid + r * 256;
      const int row = idx >> 3, c8 = idx & 7;
      const float* sa = x + (size_t)(bm * 128 + row) * 512 + kk * 64 + c8 * 8;
      float4 f0 = *(const float4*)sa;
      float4 f1 = *(const float4*)(sa + 4);
      uint4 w;
      w.x = f2bf(f0.x) | ((unsigned)f2bf(f0.y) << 16);
      w.y = f2bf(f0.z) | ((unsigned)f2bf(f0.w) << 16);
      w.z = f2bf(f1.x) | ((unsigned)f2bf(f1.y) << 16);
      w.w = f2bf(f1.z) | ((unsigned)f2bf(f1.w) << 16);
      astage[r] = w;
      bstage[r] = *(const uint4*)(wqkv + (size_t)(bn * 128 + row) * 512 + kk * 64 + c8 * 8);
    }
    __syncthreads();  // previous compute done before overwriting LDS
#pragma unroll
    for (int r = 0; r < 4; ++r) {
      const int idx = tid + r * 256;
      const int row = idx >> 3, c8 = idx & 7;
      const int off = row * 128 + ((c8 * 16) ^ ((row & 7) << 4));
      *(uint4*)(as_ + off) = astage[r];
      *(uint4*)(bs_ + off) = bstage[r];
    }
    __syncthreads();
#pragma unroll
    for (int ki = 0; ki < 2; ++ki) {
      bf16x8 af[4], bfr[4];
#pragma unroll
      for (int mt = 0; mt < 4; ++mt) {
        const int row = 64 * wm + 16 * mt + l15;
        af[mt] = *(const bf16x8*)(as_ + row * 128 + ((64 * ki + 16 * l4) ^ ((row & 7) << 4)));
      }
#pragma unroll
      for (int nt = 0; nt < 4; ++nt) {
        const int row = 64 * wn + 16 * nt + l15;
        bfr[nt] = *(const bf16x8*)(bs_ + row * 128 + ((64 * ki + 16 * l4) ^ ((row & 7) << 4)));
      }
#pragma unroll
      for (int mt = 0; mt < 4; ++mt)
#pragma unroll
        for (int nt = 0; nt < 4; ++nt)
          acc[mt][nt] = __builtin_amdgcn_mfma_f32_16x16x32_bf16(af[mt], bfr[nt], acc[mt][nt], 0, 0, 0);
    }
  }

  const int three = bn >> 2;  // 0=q 1=k 2=v (tile never spans)
  if (three < 2) {
    short* dst = (three == 0) ? q_g : k_g;
#pragma unroll
    for (int mt = 0; mt < 4; ++mt) {
      const int m0 = bm * 128 + 64 * wm + 16 * mt + 4 * l4;
      const int b = m0 >> 6, t0 = m0 & 63;
#pragma unroll
      for (int nt = 0; nt < 4; ++nt) {
        const int n = bn * 128 + 64 * wn + 16 * nt + l15;
        const int h = (n >> 6) & 7, d = n & 63;
        short* p = dst + (size_t)(b * 8 + h) * 4096 + d;
#pragma unroll
        for (int jj = 0; jj < 4; ++jj)
          p[(t0 + jj) * 64] = (short)f2bf(acc[mt][nt][jj]);
      }
    }
  } else {
#pragma unroll
    for (int mt = 0; mt < 4; ++mt) {
      const int m0 = bm * 128 + 64 * wm + 16 * mt + 4 * l4;
      const int b = m0 >> 6, t0 = m0 & 63;
#pragma unroll
      for (int nt = 0; nt < 4; ++nt) {
        const int n = bn * 128 + 64 * wn + 16 * nt + l15;
        const int h = (n >> 6) & 7, d = n & 63;
        uint2 w;
        w.x = f2bf(acc[mt][nt][0]) | ((unsigned)f2bf(acc[mt][nt][1]) << 16);
        w.y = f2bf(acc[mt][nt][2]) | ((unsigned)f2bf(acc[mt][nt][3]) << 16);
        *(uint2*)(vT_g + (size_t)((b * 8 + h) * 64 + d) * 64 + t0) = w;
      }
    }
  }
}

// ---------------------------------------------------------------------------
// attention: one block per (b,h), 4 waves; wave w owns rows [16w,16w+16).
// LDS 40KB -> 4 blocks/CU. Only 2 barriers per block.
// ---------------------------------------------------------------------------
__global__ __launch_bounds__(256, 4)
void attn_kernel(const short* __restrict__ q_g, const short* __restrict__ k_g,
                 const short* __restrict__ vT_g, const short* __restrict__ relk,
                 const short* __restrict__ relvT, short* __restrict__ aout) {
  __shared__ __align__(16) short srel_s[64 * 256];  // 32KB swizzled [i][nb]; reused as P
  __shared__ __align__(16) short attn_s[64 * 64];   // 8KB swizzled  [i][j]
  const int tid = threadIdx.x, lane = tid & 63, w = tid >> 6;
  const int l15 = lane & 15, l4 = lane >> 4;
  const int bh = blockIdx.x;
  const short* qb = q_g + (size_t)bh * 4096;
  const short* kb = k_g + (size_t)bh * 4096;
  const short* vb = vT_g + (size_t)bh * 4096;
  char* ss = (char*)srel_s;
  char* as = (char*)attn_s;
  const f32x4 fz = {0.f, 0.f, 0.f, 0.f};

  // ---- Srel^T GEMM: D[nb,i] = sum_d relk[nb,d] q[i,d]; wave w: nb-tiles 4w..4w+3
  bf16x8 bq[4][2];
#pragma unroll
  for (int nt = 0; nt < 4; ++nt)
#pragma unroll
    for (int kkk = 0; kkk < 2; ++kkk)
      bq[nt][kkk] = *(const bf16x8*)(qb + (16 * nt + l15) * 64 + 32 * kkk + 8 * l4);
#pragma unroll
  for (int mtl = 0; mtl < 4; ++mtl) {
    const int mt = 4 * w + mtl;
    bf16x8 ar0 = *(const bf16x8*)(relk + (16 * mt + l15) * 64 + 8 * l4);
    bf16x8 ar1 = *(const bf16x8*)(relk + (16 * mt + l15) * 64 + 32 + 8 * l4);
#pragma unroll
    for (int nt = 0; nt < 4; ++nt) {
      f32x4 a = fz;
      a = __builtin_amdgcn_mfma_f32_16x16x32_bf16(ar0, bq[nt][0], a, 0, 0, 0);
      a = __builtin_amdgcn_mfma_f32_16x16x32_bf16(ar1, bq[nt][1], a, 0, 0, 0);
      const int i = 16 * nt + l15;
      const int nb0 = 16 * mt + 4 * l4;
      uint2 wv;
      wv.x = f2bf(a[0]) | ((unsigned)f2bf(a[1]) << 16);
      wv.y = f2bf(a[2]) | ((unsigned)f2bf(a[3]) << 16);
      *(uint2*)(ss + i * 512 + ((nb0 * 2) ^ ((i & 7) << 4))) = wv;
    }
  }

  // ---- S^T GEMM (own strip): D[j,i] = sum_d k[j,d] q[i,d], i = 16w+l15
  f32x4 sacc[4];
#pragma unroll
  for (int jt = 0; jt < 4; ++jt) {
    sacc[jt] = fz;
    bf16x8 ak0 = *(const bf16x8*)(kb + (16 * jt + l15) * 64 + 8 * l4);
    bf16x8 ak1 = *(const bf16x8*)(kb + (16 * jt + l15) * 64 + 32 + 8 * l4);
    sacc[jt] = __builtin_amdgcn_mfma_f32_16x16x32_bf16(ak0, bq[w][0], sacc[jt], 0, 0, 0);
    sacc[jt] = __builtin_amdgcn_mfma_f32_16x16x32_bf16(ak1, bq[w][1], sacc[jt], 0, 0, 0);
  }
  __syncthreads();  // barrier 1: Srel complete

  // ---- softmax over own rows (4 lanes per row, 16 logits each) ----
  const int i = 16 * w + l15;
  const int swz = (i & 7) << 4;
  const int ri = i >> 3, fi = i & 7;
  float p[16];
  float mx = -1e30f;
#pragma unroll
  for (int jt = 0; jt < 4; ++jt)
#pragma unroll
    for (int rg = 0; rg < 4; ++rg) {
      const int j = 16 * jt + 4 * l4 + rg;
      const int nb = ((j >> 3) - ri + 7) * 15 + ((j & 7) - fi + 7);
      const float sr = bf2f(*(const unsigned short*)(ss + i * 512 + ((nb * 2) ^ swz)));
      const float lv = (sacc[jt][rg] + sr) * 0.125f;
      p[4 * jt + rg] = lv;
      mx = fmaxf(mx, lv);
    }
  mx = fmaxf(mx, __shfl_xor(mx, 16));
  mx = fmaxf(mx, __shfl_xor(mx, 32));
  float sum = 0.f;
#pragma unroll
  for (int q2 = 0; q2 < 16; ++q2) {
    p[q2] = __expf(p[q2] - mx);
    sum += p[q2];
  }
  sum += __shfl_xor(sum, 16);
  sum += __shfl_xor(sum, 32);
  const float rs = 1.0f / sum;
  unsigned short pb[16];
#pragma unroll
  for (int q2 = 0; q2 < 16; ++q2) pb[q2] = f2bf(p[q2] * rs);
  // attn_s[i][j] packed uint2
#pragma unroll
  for (int jt = 0; jt < 4; ++jt) {
    uint2 wv;
    wv.x = pb[4 * jt] | ((unsigned)pb[4 * jt + 1] << 16);
    wv.y = pb[4 * jt + 2] | ((unsigned)pb[4 * jt + 3] << 16);
    *(uint2*)(as + i * 128 + (((16 * jt + 4 * l4) * 2) ^ swz)) = wv;
  }
  {  // zero own P row (reuse Srel buffer; reads above precede in wave order)
    const uint4 uz = {0u, 0u, 0u, 0u};
#pragma unroll
    for (int c = 0; c < 8; ++c)
      *(uint4*)(ss + i * 512 + ((l4 * 128 + c * 16) ^ swz)) = uz;
  }
#pragma unroll
  for (int jt = 0; jt < 4; ++jt)  // scatter P (injective per row)
#pragma unroll
    for (int rg = 0; rg < 4; ++rg) {
      const int j = 16 * jt + 4 * l4 + rg;
      const int nb = ((j >> 3) - ri + 7) * 15 + ((j & 7) - fi + 7);
      *(unsigned short*)(ss + i * 512 + ((nb * 2) ^ swz)) = pb[4 * jt + rg];
    }
  __syncthreads();  // barrier 2: attn + P visible to all waves

  // ---- PV: D[d,t] = sum_j vT[d,j]attn[t,j] + sum_nb relvT[d,nb]P[t,nb]
  f32x4 oacc[4];
#pragma unroll
  for (int nt = 0; nt < 4; ++nt) oacc[nt] = fz;
#pragma unroll
  for (int kkk = 0; kkk < 2; ++kkk) {
    bf16x8 av = *(const bf16x8*)(vb + (16 * w + l15) * 64 + 32 * kkk + 8 * l4);
#pragma unroll
    for (int nt = 0; nt < 4; ++nt) {
      const int t = 16 * nt + l15;
      bf16x8 bp = *(const bf16x8*)(as + t * 128 + (((32 * kkk + 8 * l4) * 2) ^ ((t & 7) << 4)));
      oacc[nt] = __builtin_amdgcn_mfma_f32_16x16x32_bf16(av, bp, oacc[nt], 0, 0, 0);
    }
  }
#pragma unroll
  for (int kkk = 0; kkk < 8; ++kkk) {
    bf16x8 arv = *(const bf16x8*)(relvT + (16 * w + l15) * 256 + 32 * kkk + 8 * l4);
#pragma unroll
    for (int nt = 0; nt < 4; ++nt) {
      const int t = 16 * nt + l15;
      bf16x8 bp = *(const bf16x8*)(ss + t * 512 + (((32 * kkk + 8 * l4) * 2) ^ ((t & 7) << 4)));
      oacc[nt] = __builtin_amdgcn_mfma_f32_16x16x32_bf16(arv, bp, oacc[nt], 0, 0, 0);
    }
  }
  const int b = bh >> 3, h = bh & 7;
#pragma unroll
  for (int nt = 0; nt < 4; ++nt) {
    const int t = 16 * nt + l15;
    const int d0 = 16 * w + 4 * l4;
    uint2 wv;
    wv.x = f2bf(oacc[nt][0]) | ((unsigned)f2bf(oacc[nt][1]) << 16);
    wv.y = f2bf(oacc[nt][2]) | ((unsigned)f2bf(oacc[nt][3]) << 16);
    *(uint2*)(aout + (size_t)(b * 64 + t) * 512 + h * 64 + d0) = wv;
  }
}

// ---------------------------------------------------------------------------
// fallback fused kernel (round-0, known-good) — used only if ws too small
// ---------------------------------------------------------------------------
__global__ __launch_bounds__(512, 2)
void fused_qkv_attn(const float* __restrict__ x,
                    const short* __restrict__ wqkv,
                    const short* __restrict__ relk,
                    const short* __restrict__ relvT,
                    short* __restrict__ aout) {
  __shared__ __align__(16) short x_s[64 * 512];
  __shared__ __align__(16) short q_s[64 * 64];
  __shared__ __align__(16) short k_s[64 * 64];
  __shared__ __align__(16) short vT_s[64 * 64];
  __shared__ __align__(16) short p_s[64 * 256];
  __shared__ __align__(16) float logit_s[64 * 64];
  __shared__ __align__(16) short attn_s[64 * 64];

  const int tid = threadIdx.x;
  const int lane = tid & 63;
  const int wm = (tid >> 6) >> 2;
  const int wn = (tid >> 6) & 3;
  const int l15 = lane & 15;
  const int l4 = lane >> 4;
  const int b = blockIdx.x;

  char* xs = (char*)x_s;
  char* qs = (char*)q_s;
  char* ks = (char*)k_s;
  char* vs = (char*)vT_s;
  char* ps = (char*)p_s;
  char* as = (char*)attn_s;

  {
    const int row = tid >> 3;
    const int seg = tid & 7;
    const float* src = x + ((size_t)b * 64 + row) * 512 + seg * 64;
    char* dst = xs + row * 1024;
    const int swz = (row & 7) << 4;
#pragma unroll
    for (int i = 0; i < 8; ++i) {
      float4 f0 = *(const float4*)(src + i * 8);
      float4 f1 = *(const float4*)(src + i * 8 + 4);
      uint4 w;
      w.x = f2bf(f0.x) | ((unsigned)f2bf(f0.y) << 16);
      w.y = f2bf(f0.z) | ((unsigned)f2bf(f0.w) << 16);
      w.z = f2bf(f1.x) | ((unsigned)f2bf(f1.y) << 16);
      w.w = f2bf(f1.z) | ((unsigned)f2bf(f1.w) << 16);
      const int col2 = (seg * 64 + i * 8) * 2;
      *(uint4*)(dst + (col2 ^ swz)) = w;
    }
  }
  __syncthreads();

  const f32x4 fz = {0.f, 0.f, 0.f, 0.f};

  for (int h = 0; h < 8; ++h) {
    f32x4 acc1[2][3];
#pragma unroll
    for (int mi = 0; mi < 2; ++mi)
#pragma unroll
      for (int r = 0; r < 3; ++r) acc1[mi][r] = fz;

#pragma unroll 2
    for (int kk = 0; kk < 16; ++kk) {
      bf16x8 av[2], bv[3];
#pragma unroll
      for (int mi = 0; mi < 2; ++mi) {
        const int row = 16 * (2 * wm + mi) + l15;
        const int col2 = (32 * kk + 8 * l4) * 2;
        av[mi] = *(const bf16x8*)(xs + row * 1024 + (col2 ^ ((row & 7) << 4)));
      }
#pragma unroll
      for (int r = 0; r < 3; ++r) {
        const int nt = 3 * wn + r;
        const int nrow = (nt >> 2) * 512 + h * 64 + (nt & 3) * 16 + l15;
        bv[r] = *(const bf16x8*)(wqkv + (size_t)nrow * 512 + 32 * kk + 8 * l4);
      }
#pragma unroll
      for (int mi = 0; mi < 2; ++mi)
#pragma unroll
        for (int r = 0; r < 3; ++r)
          acc1[mi][r] = __builtin_amdgcn_mfma_f32_16x16x32_bf16(av[mi], bv[r], acc1[mi][r], 0, 0, 0);
    }
#pragma unroll
    for (int mi = 0; mi < 2; ++mi) {
      const int r0 = 16 * (2 * wm + mi) + 4 * l4;
#pragma unroll
      for (int r = 0; r < 3; ++r) {
        const int nt = 3 * wn + r;
        const int three = nt >> 2;
        const int col = (nt & 3) * 16 + l15;
        if (three == 2) {
          uint2 w;
          w.x = f2bf(acc1[mi][r][0]) | ((unsigned)f2bf(acc1[mi][r][1]) << 16);
          w.y = f2bf(acc1[mi][r][2]) | ((unsigned)f2bf(acc1[mi][r][3]) << 16);
          *(uint2*)(vs + col * 128 + ((r0 * 2) ^ ((col & 7) << 4))) = w;
        } else {
          char* base = (three == 0) ? qs : ks;
#pragma unroll
          for (int jj = 0; jj < 4; ++jj) {
            const int row = r0 + jj;
            *(unsigned short*)(base + row * 128 + ((col * 2) ^ ((row & 7) << 4))) =
                f2bf(acc1[mi][r][jj]);
          }
        }
      }
    }
    __syncthreads();

    f32x4 acc2[2][5];
#pragma unroll
    for (int mi = 0; mi < 2; ++mi)
#pragma unroll
      for (int r = 0; r < 5; ++r) acc2[mi][r] = fz;

#pragma unroll
    for (int kk = 0; kk < 2; ++kk) {
      bf16x8 av[2], bv[5];
      const int col2 = (32 * kk + 8 * l4) * 2;
#pragma unroll
      for (int mi = 0; mi < 2; ++mi) {
        const int row = 16 * (2 * wm + mi) + l15;
        av[mi] = *(const bf16x8*)(qs + row * 128 + (col2 ^ ((row & 7) << 4)));
      }
#pragma unroll
      for (int r = 0; r < 5; ++r) {
        const int nt = 5 * wn + r;
        if (nt < 4) {
          const int row = 16 * nt + l15;
          bv[r] = *(const bf16x8*)(ks + row * 128 + (col2 ^ ((row & 7) << 4)));
        } else {
          const int nb = (nt - 4) * 16 + l15;
          bv[r] = *(const bf16x8*)(relk + nb * 64 + 32 * kk + 8 * l4);
        }
      }
#pragma unroll
      for (int mi = 0; mi < 2; ++mi)
#pragma unroll
        for (int r = 0; r < 5; ++r)
          acc2[mi][r] = __builtin_amdgcn_mfma_f32_16x16x32_bf16(av[mi], bv[r], acc2[mi][r], 0, 0, 0);
    }
#pragma unroll
    for (int mi = 0; mi < 2; ++mi) {
      const int r0 = 16 * (2 * wm + mi) + 4 * l4;
#pragma unroll
      for (int r = 0; r < 5; ++r) {
        const int nt = 5 * wn + r;
        if (nt < 4) {
          const int j0 = 16 * nt + l15;
#pragma unroll
          for (int jj = 0; jj < 4; ++jj) logit_s[(r0 + jj) * 64 + j0] = acc2[mi][r][jj];
        } else {
          const int nb = (nt - 4) * 16 + l15;
#pragma unroll
          for (int jj = 0; jj < 4; ++jj) {
            const int row = r0 + jj;
            *(unsigned short*)(ps + row * 512 + ((nb * 2) ^ ((row & 7) << 4))) =
                f2bf(acc2[mi][r][jj]);
          }
        }
      }
    }
    __syncthreads();

    const int i = tid >> 3;
    const int g = tid & 7;
    float pv[8];
    int nbv[8];
    {
      const float* lr = logit_s + i * 64 + g * 8;
      const int ri = i >> 3, fi = i & 7;
      float mx = -1e30f;
#pragma unroll
      for (int jj = 0; jj < 8; ++jj) {
        const int j = g * 8 + jj;
        const int nb = ((j >> 3) - ri + 7) * 15 + ((j & 7) - fi + 7);
        nbv[jj] = nb;
        const float sr = bf2f(*(const unsigned short*)(ps + i * 512 + ((nb * 2) ^ ((i & 7) << 4))));
        const float lv = (lr[jj] + sr) * 0.125f;
        pv[jj] = lv;
        mx = fmaxf(mx, lv);
      }
      mx = fmaxf(mx, __shfl_xor(mx, 1));
      mx = fmaxf(mx, __shfl_xor(mx, 2));
      mx = fmaxf(mx, __shfl_xor(mx, 4));
      float sum = 0.f;
#pragma unroll
      for (int jj = 0; jj < 8; ++jj) {
        pv[jj] = __expf(pv[jj] - mx);
        sum += pv[jj];
      }
      sum += __shfl_xor(sum, 1);
      sum += __shfl_xor(sum, 2);
      sum += __shfl_xor(sum, 4);
      const float rs = 1.0f / sum;
      unsigned wv0[4];
#pragma unroll
      for (int k2 = 0; k2 < 4; ++k2) {
        float a0 = pv[2 * k2] * rs, a1 = pv[2 * k2 + 1] * rs;
        pv[2 * k2] = a0;
        pv[2 * k2 + 1] = a1;
        wv0[k2] = f2bf(a0) | ((unsigned)f2bf(a1) << 16);
      }
      uint4 w;
      w.x = wv0[0]; w.y = wv0[1]; w.z = wv0[2]; w.w = wv0[3];
      *(uint4*)(as + i * 128 + ((g * 16) ^ ((i & 7) << 4))) = w;
    }
    __syncthreads();
    {
      const uint4 uz = {0u, 0u, 0u, 0u};
#pragma unroll
      for (int c = 0; c < 4; ++c) *(uint4*)(ps + tid * 64 + c * 16) = uz;
    }
    __syncthreads();
#pragma unroll
    for (int jj = 0; jj < 8; ++jj)
      *(unsigned short*)(ps + i * 512 + ((nbv[jj] * 2) ^ ((i & 7) << 4))) = f2bf(pv[jj]);
    __syncthreads();

    f32x4 acc3[2];
    acc3[0] = fz;
    acc3[1] = fz;
#pragma unroll
    for (int kk = 0; kk < 10; ++kk) {
      bf16x8 av[2], bv;
      if (kk < 2) {
        const int c2 = (32 * kk + 8 * l4) * 2;
#pragma unroll
        for (int mi = 0; mi < 2; ++mi) {
          const int row = 16 * (2 * wm + mi) + l15;
          av[mi] = *(const bf16x8*)(as + row * 128 + (c2 ^ ((row & 7) << 4)));
        }
        const int dr = 16 * wn + l15;
        bv = *(const bf16x8*)(vs + dr * 128 + (c2 ^ ((dr & 7) << 4)));
      } else {
        const int c2 = (32 * (kk - 2) + 8 * l4) * 2;
#pragma unroll
        for (int mi = 0; mi < 2; ++mi) {
          const int row = 16 * (2 * wm + mi) + l15;
          av[mi] = *(const bf16x8*)(ps + row * 512 + (c2 ^ ((row & 7) << 4)));
        }
        const int dr = 16 * wn + l15;
        bv = *(const bf16x8*)(relvT + dr * 256 + 32 * (kk - 2) + 8 * l4);
      }
      acc3[0] = __builtin_amdgcn_mfma_f32_16x16x32_bf16(av[0], bv, acc3[0], 0, 0, 0);
      acc3[1] = __builtin_amdgcn_mfma_f32_16x16x32_bf16(av[1], bv, acc3[1], 0, 0, 0);
    }
#pragma unroll
    for (int mi = 0; mi < 2; ++mi) {
      const int r0 = 16 * (2 * wm + mi) + 4 * l4;
      const int col = h * 64 + 16 * wn + l15;
#pragma unroll
      for (int jj = 0; jj < 4; ++jj)
        aout[((size_t)b * 64 + r0 + jj) * 512 + col] = (short)f2bf(acc3[mi][jj]);
    }
    __syncthreads();
  }
}

// ---------------------------------------------------------------------------
// proj: out = aout(bf16) @ w_proj^T + b_proj (unchanged from round 0)
// ---------------------------------------------------------------------------
__global__ __launch_bounds__(256)
void proj_kernel(const short* __restrict__ aout, const short* __restrict__ wproj,
                 const float* __restrict__ bproj, float* __restrict__ out) {
  __shared__ __align__(16) short As[128 * 64];
  __shared__ __align__(16) short Bs[128 * 64];
  const int tid = threadIdx.x;
  const int lane = tid & 63;
  const int wave = tid >> 6;
  const int wm = wave >> 1, wn = wave & 1;
  const int l15 = lane & 15, l4 = lane >> 4;
  const int bm = blockIdx.x, bn = blockIdx.y;
  char* as_ = (char*)As;
  char* bs_ = (char*)Bs;

  const f32x4 fz = {0.f, 0.f, 0.f, 0.f};
  f32x4 acc[4][4];
#pragma unroll
  for (int mt = 0; mt < 4; ++mt)
#pragma unroll
    for (int nt = 0; nt < 4; ++nt) acc[mt][nt] = fz;

  for (int kk = 0; kk < 8; ++kk) {
#pragma unroll
    for (int c = 0; c < 4; ++c) {
      const int off = (tid * 4 + c) * 16;
      const int row = off >> 7;
      const int lg = ((off >> 4) & 7) ^ (row & 7);
      const short* gA = aout + ((size_t)(bm * 128 + row)) * 512 + kk * 64 + lg * 8;
      const short* gB = wproj + ((size_t)(bn * 128 + row)) * 512 + kk * 64 + lg * 8;
      *(uint4*)(as_ + off) = *(const uint4*)gA;
      *(uint4*)(bs_ + off) = *(const uint4*)gB;
    }
    __syncthreads();
#pragma unroll
    for (int ki = 0; ki < 2; ++ki) {
      bf16x8 af[4], bq[4];
#pragma unroll
      for (int mt = 0; mt < 4; ++mt) {
        const int row = 64 * wm + 16 * mt + l15;
        const int col2 = 64 * ki + 16 * l4;
        af[mt] = *(const bf16x8*)(as_ + row * 128 + (col2 ^ ((row & 7) << 4)));
      }
#pragma unroll
      for (int nt = 0; nt < 4; ++nt) {
        const int row = 64 * wn + 16 * nt + l15;
        const int col2 = 64 * ki + 16 * l4;
        bq[nt] = *(const bf16x8*)(bs_ + row * 128 + (col2 ^ ((row & 7) << 4)));
      }
#pragma unroll
      for (int mt = 0; mt < 4; ++mt)
#pragma unroll
        for (int nt = 0; nt < 4; ++nt)
          acc[mt][nt] = __builtin_amdgcn_mfma_f32_16x16x32_bf16(af[mt], bq[nt], acc[mt][nt], 0, 0, 0);
    }
    __syncthreads();
  }
#pragma unroll
  for (int nt = 0; nt < 4; ++nt) {
    const int col = bn * 128 + 64 * wn + 16 * nt + l15;
    const float bias = bproj[col];
#pragma unroll
    for (int mt = 0; mt < 4; ++mt) {
      const int r0 = bm * 128 + 64 * wm + 16 * mt + 4 * l4;
#pragma unroll
      for (int jj = 0; jj < 4; ++jj)
        out[(size_t)(r0 + jj) * 512 + col] = acc[mt][nt][jj] + bias;
    }
  }
}

// ---------------------------------------------------------------------------
extern "C" void kernel_launch(void* const* d_in, const int* in_sizes, int n_in,
                              void* d_out, int out_size, void* d_ws, size_t ws_size,
                              hipStream_t stream) {
  const float* x = (const float*)d_in[0];
  const float* wqkv = (const float*)d_in[1];
  const float* wproj = (const float*)d_in[2];
  const float* bproj = (const float*)d_in[3];
  const float* relk = (const float*)d_in[4];
  const float* relv = (const float*)d_in[5];
  float* out = (float*)d_out;

  char* ws = (char*)d_ws;
  const size_t MB = 1024 * 1024;
  const int split = (ws_size >= 137 * MB) ? 1 : 0;

  short* aout = (short*)ws;  // 64MB, both paths
  const size_t tab = split ? 128 * MB : 64 * MB;
  short* wqkv_b = (short*)(ws + tab);                   // 1.5MB
  short* wproj_b = (short*)(ws + tab + 1572864);        // 0.5MB
  short* relk_b = (short*)(ws + tab + 2097152);         // 32KB
  short* relvT_b = (short*)(ws + tab + 2129920);        // 32KB

  prep_kernel<<<dim3(768), dim3(256), 0, stream>>>(wqkv, wproj, relk, relv, wqkv_b,
                                                   wproj_b, relk_b, relvT_b);
  if (split) {
    // q,k live in d_out (128MB) until proj overwrites it; vT in ws
    short* q_gg = (short*)d_out;
    short* k_gg = (short*)((char*)d_out + 64 * MB);
    short* vT_g = (short*)(ws + 64 * MB);
    qkv_gemm<<<dim3(6144), dim3(256), 0, stream>>>(x, wqkv_b, q_gg, k_gg, vT_g);
    attn_kernel<<<dim3(8192), dim3(256), 0, stream>>>(q_gg, k_gg, vT_g, relk_b, relvT_b, aout);
  } else {
    fused_qkv_attn<<<dim3(1024), dim3(512), 0, stream>>>(x, wqkv_b, relk_b, relvT_b, aout);
  }
  proj_kernel<<<dim3(512, 4), dim3(256), 0, stream>>>(aout, wproj_b, bproj, out);
}

// Round 3
// 385.650 us; speedup vs baseline: 1.5906x; 1.5796x over previous
//
#include <hip/hip_runtime.h>
#include <stdint.h>
#include <stddef.h>

typedef __attribute__((ext_vector_type(8))) short bf16x8;
typedef __attribute__((ext_vector_type(4))) float f32x4;

typedef __attribute__((address_space(1))) const unsigned int g_as1;
typedef __attribute__((address_space(3))) unsigned int lds_as3;
__device__ __forceinline__ void gload_lds16(const void* g, void* l) {
  __builtin_amdgcn_global_load_lds((g_as1*)g, (lds_as3*)l, 16, 0, 0);
}

__device__ __forceinline__ unsigned short f2bf(float f) {
  union { float f; unsigned int u; } v; v.f = f;
  unsigned int u = v.u;
  u += 0x7fffu + ((u >> 16) & 1u);   // round-to-nearest-even
  return (unsigned short)(u >> 16);
}
__device__ __forceinline__ float bf2f(unsigned short s) {
  union { unsigned int u; float f; } v; v.u = ((unsigned int)s) << 16;
  return v.f;
}

// Tile image layout: a (bm,kk) tile of 128 rows x 64 cols bf16 occupies 16KB;
// element (r,c) at byte  r*128 + ((c*2) ^ ((r&7)<<4)).  This equals the
// swizzled LDS image, so linear global_load_lds reproduces it in LDS.

// ---------------------------------------------------------------------------
// prep: wqkv -> tile image [bn=12][kk=8]; wproj -> tile image [bn=4][kk=8];
//       relk_b [256][64] plain (rows>=225 zero); relvT_b [64][256] plain.
// grid 528 x 256, one 16B granule (or equivalent) per thread.
// ---------------------------------------------------------------------------
__global__ void prep_kernel(const float* __restrict__ wqkv,
                            const float* __restrict__ wproj,
                            const float* __restrict__ relk,
                            const float* __restrict__ relv,
                            short* __restrict__ wq_t,
                            short* __restrict__ wp_t,
                            short* __restrict__ relk_b,
                            short* __restrict__ relvT_b) {
  const int g = blockIdx.x * 256 + threadIdx.x;  // 0..135167
  if (g < 98304) {  // wqkv: 1536 rows x 64 granules
    const int row = g >> 6, c8 = g & 63;
    const float* s = wqkv + (size_t)row * 512 + c8 * 8;
    float4 f0 = *(const float4*)s;
    float4 f1 = *(const float4*)(s + 4);
    uint4 w;
    w.x = f2bf(f0.x) | ((unsigned)f2bf(f0.y) << 16);
    w.y = f2bf(f0.z) | ((unsigned)f2bf(f0.w) << 16);
    w.z = f2bf(f1.x) | ((unsigned)f2bf(f1.y) << 16);
    w.w = f2bf(f1.z) | ((unsigned)f2bf(f1.w) << 16);
    const int bn = row >> 7, rl = row & 127, kk = c8 >> 3, c8l = c8 & 7;
    char* d = (char*)wq_t + (size_t)(bn * 8 + kk) * 16384 + rl * 128 +
              ((c8l * 16) ^ ((rl & 7) << 4));
    *(uint4*)d = w;
  } else if (g < 131072) {  // wproj: 512 rows x 64 granules
    const int g2 = g - 98304;
    const int row = g2 >> 6, c8 = g2 & 63;
    const float* s = wproj + (size_t)row * 512 + c8 * 8;
    float4 f0 = *(const float4*)s;
    float4 f1 = *(const float4*)(s + 4);
    uint4 w;
    w.x = f2bf(f0.x) | ((unsigned)f2bf(f0.y) << 16);
    w.y = f2bf(f0.z) | ((unsigned)f2bf(f0.w) << 16);
    w.z = f2bf(f1.x) | ((unsigned)f2bf(f1.y) << 16);
    w.w = f2bf(f1.z) | ((unsigned)f2bf(f1.w) << 16);
    const int bn = row >> 7, rl = row & 127, kk = c8 >> 3, c8l = c8 & 7;
    char* d = (char*)wp_t + (size_t)(bn * 8 + kk) * 16384 + rl * 128 +
              ((c8l * 16) ^ ((rl & 7) << 4));
    *(uint4*)d = w;
  } else if (g < 133120) {  // relk: 256 rows x 8 granules
    const int g3 = g - 131072;
    const int nb = g3 >> 3, c8 = g3 & 7;
    uint4 w = {0u, 0u, 0u, 0u};
    if (nb < 225) {
      const float* s = relk + (size_t)nb * 64 + c8 * 8;
      float4 f0 = *(const float4*)s;
      float4 f1 = *(const float4*)(s + 4);
      w.x = f2bf(f0.x) | ((unsigned)f2bf(f0.y) << 16);
      w.y = f2bf(f0.z) | ((unsigned)f2bf(f0.w) << 16);
      w.z = f2bf(f1.x) | ((unsigned)f2bf(f1.y) << 16);
      w.w = f2bf(f1.z) | ((unsigned)f2bf(f1.w) << 16);
    }
    *(uint4*)(relk_b + nb * 64 + c8 * 8) = w;
  } else {  // relvT: 64 d-rows x 32 granules of 8
    const int g4 = g - 133120;
    const int d = g4 >> 5, nb0 = (g4 & 31) * 8;
    unsigned short s[8];
#pragma unroll
    for (int j = 0; j < 8; ++j) {
      const int nb = nb0 + j;
      s[j] = (nb < 225) ? f2bf(relv[(size_t)nb * 64 + d]) : (unsigned short)0;
    }
    uint4 w;
    w.x = s[0] | ((unsigned)s[1] << 16);
    w.y = s[2] | ((unsigned)s[3] << 16);
    w.z = s[4] | ((unsigned)s[5] << 16);
    w.w = s[6] | ((unsigned)s[7] << 16);
    *(uint4*)(relvT_b + d * 256 + nb0) = w;
  }
}

// ---------------------------------------------------------------------------
// xconv: x fp32 [65536][512] -> bf16 tile image [bm=512][kk=8].
// grid 16384 x 256, one granule per thread. Pure streaming.
// ---------------------------------------------------------------------------
__global__ void xconv_kernel(const float* __restrict__ x, short* __restrict__ x_t) {
  const int g = blockIdx.x * 256 + threadIdx.x;  // 0..4194303
  const int row = g >> 6, c8 = g & 63;
  const float* s = x + (size_t)row * 512 + c8 * 8;
  float4 f0 = *(const float4*)s;
  float4 f1 = *(const float4*)(s + 4);
  uint4 w;
  w.x = f2bf(f0.x) | ((unsigned)f2bf(f0.y) << 16);
  w.y = f2bf(f0.z) | ((unsigned)f2bf(f0.w) << 16);
  w.z = f2bf(f1.x) | ((unsigned)f2bf(f1.y) << 16);
  w.w = f2bf(f1.z) | ((unsigned)f2bf(f1.w) << 16);
  const int bm = row >> 7, rl = row & 127, kk = c8 >> 3, c8l = c8 & 7;
  char* d = (char*)x_t + (size_t)(bm * 8 + kk) * 16384 + rl * 128 +
            ((c8l * 16) ^ ((rl & 7) << 4));
  *(uint4*)d = w;
}

// ---------------------------------------------------------------------------
// QKV GEMM (m97 structure): M=65536, N=1536, K=512. A,B pre-tiled bf16.
// 128x128 tile, BK=64, 4 waves, global_load_lds staging, 2 barriers/K-step.
// Outputs: q_g,k_g [bh][t][d], vT_g [bh][d][t].
// ---------------------------------------------------------------------------
__global__ __launch_bounds__(256)
void qkv_gemm(const short* __restrict__ x_t, const short* __restrict__ wq_t,
              short* __restrict__ q_g, short* __restrict__ k_g,
              short* __restrict__ vT_g) {
  __shared__ __align__(16) short As[8192];  // 16KB
  __shared__ __align__(16) short Bs[8192];  // 16KB
  const int tid = threadIdx.x;
  const int lane = tid & 63;
  const int l15 = lane & 15, l4 = lane >> 4;
  const int wave = tid >> 6;
  const int wm = wave >> 1, wn = wave & 1;
  const int bid = blockIdx.x;  // 6144
  const int wg = (bid & 7) * 768 + (bid >> 3);
  const int bn = wg % 12;
  const int bm = wg / 12;
  char* as_ = (char*)As;
  char* bs_ = (char*)Bs;
  const char* abase = (const char*)x_t + (size_t)bm * 131072;
  const char* bbase = (const char*)wq_t + (size_t)bn * 131072;
  const int soff = tid * 16;

  const f32x4 fz = {0.f, 0.f, 0.f, 0.f};
  f32x4 acc[4][4];
#pragma unroll
  for (int mt = 0; mt < 4; ++mt)
#pragma unroll
    for (int nt = 0; nt < 4; ++nt) acc[mt][nt] = fz;

#pragma unroll 1
  for (int kk = 0; kk < 8; ++kk) {
    const char* ga = abase + kk * 16384 + soff;
    const char* gb = bbase + kk * 16384 + soff;
#pragma unroll
    for (int i = 0; i < 4; ++i) {
      gload_lds16(ga + i * 4096, as_ + soff + i * 4096);
      gload_lds16(gb + i * 4096, bs_ + soff + i * 4096);
    }
    __syncthreads();
#pragma unroll
    for (int ki = 0; ki < 2; ++ki) {
      bf16x8 af[4], bfr[4];
#pragma unroll
      for (int mt = 0; mt < 4; ++mt) {
        const int row = 64 * wm + 16 * mt + l15;
        af[mt] = *(const bf16x8*)(as_ + row * 128 + ((64 * ki + 16 * l4) ^ ((row & 7) << 4)));
      }
#pragma unroll
      for (int nt = 0; nt < 4; ++nt) {
        const int row = 64 * wn + 16 * nt + l15;
        bfr[nt] = *(const bf16x8*)(bs_ + row * 128 + ((64 * ki + 16 * l4) ^ ((row & 7) << 4)));
      }
#pragma unroll
      for (int mt = 0; mt < 4; ++mt)
#pragma unroll
        for (int nt = 0; nt < 4; ++nt)
          acc[mt][nt] = __builtin_amdgcn_mfma_f32_16x16x32_bf16(af[mt], bfr[nt], acc[mt][nt], 0, 0, 0);
    }
    __syncthreads();
  }

  const int three = bn >> 2;  // 0=q 1=k 2=v
  if (three < 2) {
    short* dst = (three == 0) ? q_g : k_g;
#pragma unroll
    for (int mt = 0; mt < 4; ++mt) {
      const int m0 = bm * 128 + 64 * wm + 16 * mt + 4 * l4;
      const int b = m0 >> 6, t0 = m0 & 63;
#pragma unroll
      for (int nt = 0; nt < 4; ++nt) {
        const int n = bn * 128 + 64 * wn + 16 * nt + l15;
        const int h = (n >> 6) & 7, d = n & 63;
        short* p = dst + (size_t)(b * 8 + h) * 4096 + d;
#pragma unroll
        for (int jj = 0; jj < 4; ++jj)
          p[(t0 + jj) * 64] = (short)f2bf(acc[mt][nt][jj]);
      }
    }
  } else {
#pragma unroll
    for (int mt = 0; mt < 4; ++mt) {
      const int m0 = bm * 128 + 64 * wm + 16 * mt + 4 * l4;
      const int b = m0 >> 6, t0 = m0 & 63;
#pragma unroll
      for (int nt = 0; nt < 4; ++nt) {
        const int n = bn * 128 + 64 * wn + 16 * nt + l15;
        const int h = (n >> 6) & 7, d = n & 63;
        uint2 w;
        w.x = f2bf(acc[mt][nt][0]) | ((unsigned)f2bf(acc[mt][nt][1]) << 16);
        w.y = f2bf(acc[mt][nt][2]) | ((unsigned)f2bf(acc[mt][nt][3]) << 16);
        *(uint2*)(vT_g + (size_t)((b * 8 + h) * 64 + d) * 64 + t0) = w;
      }
    }
  }
}

// ---------------------------------------------------------------------------
// attention: one block per (b,h), 4 waves; wave w owns rows [16w,16w+16).
// Epilogue writes aout in proj's tile-image layout.
// ---------------------------------------------------------------------------
__global__ __launch_bounds__(256, 4)
void attn_kernel(const short* __restrict__ q_g, const short* __restrict__ k_g,
                 const short* __restrict__ vT_g, const short* __restrict__ relk,
                 const short* __restrict__ relvT, short* __restrict__ aout_t) {
  __shared__ __align__(16) short srel_s[64 * 256];  // 32KB swizzled [i][nb]; reused as P
  __shared__ __align__(16) short attn_s[64 * 64];   // 8KB swizzled  [i][j]
  const int tid = threadIdx.x, lane = tid & 63, w = tid >> 6;
  const int l15 = lane & 15, l4 = lane >> 4;
  const int bh = blockIdx.x;
  const short* qb = q_g + (size_t)bh * 4096;
  const short* kb = k_g + (size_t)bh * 4096;
  const short* vb = vT_g + (size_t)bh * 4096;
  char* ss = (char*)srel_s;
  char* as = (char*)attn_s;
  const f32x4 fz = {0.f, 0.f, 0.f, 0.f};

  // ---- Srel^T: D[nb,i] = sum_d relk[nb,d] q[i,d]
  bf16x8 bq[4][2];
#pragma unroll
  for (int nt = 0; nt < 4; ++nt)
#pragma unroll
    for (int kkk = 0; kkk < 2; ++kkk)
      bq[nt][kkk] = *(const bf16x8*)(qb + (16 * nt + l15) * 64 + 32 * kkk + 8 * l4);
#pragma unroll
  for (int mtl = 0; mtl < 4; ++mtl) {
    const int mt = 4 * w + mtl;
    bf16x8 ar0 = *(const bf16x8*)(relk + (16 * mt + l15) * 64 + 8 * l4);
    bf16x8 ar1 = *(const bf16x8*)(relk + (16 * mt + l15) * 64 + 32 + 8 * l4);
#pragma unroll
    for (int nt = 0; nt < 4; ++nt) {
      f32x4 a = fz;
      a = __builtin_amdgcn_mfma_f32_16x16x32_bf16(ar0, bq[nt][0], a, 0, 0, 0);
      a = __builtin_amdgcn_mfma_f32_16x16x32_bf16(ar1, bq[nt][1], a, 0, 0, 0);
      const int i = 16 * nt + l15;
      const int nb0 = 16 * mt + 4 * l4;
      uint2 wv;
      wv.x = f2bf(a[0]) | ((unsigned)f2bf(a[1]) << 16);
      wv.y = f2bf(a[2]) | ((unsigned)f2bf(a[3]) << 16);
      *(uint2*)(ss + i * 512 + ((nb0 * 2) ^ ((i & 7) << 4))) = wv;
    }
  }

  // ---- S^T (own strip): D[j,i] = sum_d k[j,d] q[i,d], i = 16w+l15
  f32x4 sacc[4];
#pragma unroll
  for (int jt = 0; jt < 4; ++jt) {
    sacc[jt] = fz;
    bf16x8 ak0 = *(const bf16x8*)(kb + (16 * jt + l15) * 64 + 8 * l4);
    bf16x8 ak1 = *(const bf16x8*)(kb + (16 * jt + l15) * 64 + 32 + 8 * l4);
    sacc[jt] = __builtin_amdgcn_mfma_f32_16x16x32_bf16(ak0, bq[w][0], sacc[jt], 0, 0, 0);
    sacc[jt] = __builtin_amdgcn_mfma_f32_16x16x32_bf16(ak1, bq[w][1], sacc[jt], 0, 0, 0);
  }
  __syncthreads();  // barrier 1: Srel complete

  // ---- softmax over own rows (4 lanes per row, 16 logits each) ----
  const int i = 16 * w + l15;
  const int swz = (i & 7) << 4;
  const int ri = i >> 3, fi = i & 7;
  float p[16];
  float mx = -1e30f;
#pragma unroll
  for (int jt = 0; jt < 4; ++jt)
#pragma unroll
    for (int rg = 0; rg < 4; ++rg) {
      const int j = 16 * jt + 4 * l4 + rg;
      const int nb = ((j >> 3) - ri + 7) * 15 + ((j & 7) - fi + 7);
      const float sr = bf2f(*(const unsigned short*)(ss + i * 512 + ((nb * 2) ^ swz)));
      const float lv = (sacc[jt][rg] + sr) * 0.125f;
      p[4 * jt + rg] = lv;
      mx = fmaxf(mx, lv);
    }
  mx = fmaxf(mx, __shfl_xor(mx, 16));
  mx = fmaxf(mx, __shfl_xor(mx, 32));
  float sum = 0.f;
#pragma unroll
  for (int q2 = 0; q2 < 16; ++q2) {
    p[q2] = __expf(p[q2] - mx);
    sum += p[q2];
  }
  sum += __shfl_xor(sum, 16);
  sum += __shfl_xor(sum, 32);
  const float rs = 1.0f / sum;
  unsigned short pb[16];
#pragma unroll
  for (int q2 = 0; q2 < 16; ++q2) pb[q2] = f2bf(p[q2] * rs);
#pragma unroll
  for (int jt = 0; jt < 4; ++jt) {
    uint2 wv;
    wv.x = pb[4 * jt] | ((unsigned)pb[4 * jt + 1] << 16);
    wv.y = pb[4 * jt + 2] | ((unsigned)pb[4 * jt + 3] << 16);
    *(uint2*)(as + i * 128 + (((16 * jt + 4 * l4) * 2) ^ swz)) = wv;
  }
  {  // zero own P row (reuse Srel buffer)
    const uint4 uz = {0u, 0u, 0u, 0u};
#pragma unroll
    for (int c = 0; c < 8; ++c)
      *(uint4*)(ss + i * 512 + ((l4 * 128 + c * 16) ^ swz)) = uz;
  }
#pragma unroll
  for (int jt = 0; jt < 4; ++jt)  // scatter P (injective per row)
#pragma unroll
    for (int rg = 0; rg < 4; ++rg) {
      const int j = 16 * jt + 4 * l4 + rg;
      const int nb = ((j >> 3) - ri + 7) * 15 + ((j & 7) - fi + 7);
      *(unsigned short*)(ss + i * 512 + ((nb * 2) ^ swz)) = pb[4 * jt + rg];
    }
  __syncthreads();  // barrier 2

  // ---- PV: D[d,t] = sum_j vT[d,j]attn[t,j] + sum_nb relvT[d,nb]P[t,nb]
  f32x4 oacc[4];
#pragma unroll
  for (int nt = 0; nt < 4; ++nt) oacc[nt] = fz;
#pragma unroll
  for (int kkk = 0; kkk < 2; ++kkk) {
    bf16x8 av = *(const bf16x8*)(vb + (16 * w + l15) * 64 + 32 * kkk + 8 * l4);
#pragma unroll
    for (int nt = 0; nt < 4; ++nt) {
      const int t = 16 * nt + l15;
      bf16x8 bp = *(const bf16x8*)(as + t * 128 + (((32 * kkk + 8 * l4) * 2) ^ ((t & 7) << 4)));
      oacc[nt] = __builtin_amdgcn_mfma_f32_16x16x32_bf16(av, bp, oacc[nt], 0, 0, 0);
    }
  }
#pragma unroll
  for (int kkk = 0; kkk < 8; ++kkk) {
    bf16x8 arv = *(const bf16x8*)(relvT + (16 * w + l15) * 256 + 32 * kkk + 8 * l4);
#pragma unroll
    for (int nt = 0; nt < 4; ++nt) {
      const int t = 16 * nt + l15;
      bf16x8 bp = *(const bf16x8*)(ss + t * 512 + (((32 * kkk + 8 * l4) * 2) ^ ((t & 7) << 4)));
      oacc[nt] = __builtin_amdgcn_mfma_f32_16x16x32_bf16(arv, bp, oacc[nt], 0, 0, 0);
    }
  }
  // epilogue: write into proj tile image. global row m = b*64+t; tile bm=m>>7,
  // kk = h; in-tile r = (b&1)*64 + t, c = d.
  const int b = bh >> 3, h = bh & 7;
  char* abase = (char*)aout_t + (size_t)((b >> 1) * 8 + h) * 16384;
  const int rbase = (b & 1) * 64;
#pragma unroll
  for (int nt = 0; nt < 4; ++nt) {
    const int t = 16 * nt + l15;
    const int r = rbase + t;
    const int d0 = 16 * w + 4 * l4;
    uint2 wv;
    wv.x = f2bf(oacc[nt][0]) | ((unsigned)f2bf(oacc[nt][1]) << 16);
    wv.y = f2bf(oacc[nt][2]) | ((unsigned)f2bf(oacc[nt][3]) << 16);
    *(uint2*)(abase + r * 128 + ((d0 * 2) ^ ((r & 7) << 4))) = wv;
  }
}

// ---------------------------------------------------------------------------
// proj (m97 structure): out = aout(bf16,tiled) @ wproj^T(tiled) + b_proj.
// M=65536 N=512 K=512, 128x128 tile, fp32 out.
// ---------------------------------------------------------------------------
__global__ __launch_bounds__(256)
void proj_kernel(const short* __restrict__ a_t, const short* __restrict__ wp_t,
                 const float* __restrict__ bproj, float* __restrict__ out) {
  __shared__ __align__(16) short As[8192];
  __shared__ __align__(16) short Bs[8192];
  const int tid = threadIdx.x;
  const int lane = tid & 63;
  const int wave = tid >> 6;
  const int wm = wave >> 1, wn = wave & 1;
  const int l15 = lane & 15, l4 = lane >> 4;
  const int bid = blockIdx.x;  // 2048
  const int wg = (bid & 7) * 256 + (bid >> 3);
  const int bn = wg & 3;
  const int bm = wg >> 2;
  char* as_ = (char*)As;
  char* bs_ = (char*)Bs;
  const char* abase = (const char*)a_t + (size_t)bm * 131072;
  const char* bbase = (const char*)wp_t + (size_t)bn * 131072;
  const int soff = tid * 16;

  const f32x4 fz = {0.f, 0.f, 0.f, 0.f};
  f32x4 acc[4][4];
#pragma unroll
  for (int mt = 0; mt < 4; ++mt)
#pragma unroll
    for (int nt = 0; nt < 4; ++nt) acc[mt][nt] = fz;

#pragma unroll 1
  for (int kk = 0; kk < 8; ++kk) {
    const char* ga = abase + kk * 16384 + soff;
    const char* gb = bbase + kk * 16384 + soff;
#pragma unroll
    for (int i = 0; i < 4; ++i) {
      gload_lds16(ga + i * 4096, as_ + soff + i * 4096);
      gload_lds16(gb + i * 4096, bs_ + soff + i * 4096);
    }
    __syncthreads();
#pragma unroll
    for (int ki = 0; ki < 2; ++ki) {
      bf16x8 af[4], bq[4];
#pragma unroll
      for (int mt = 0; mt < 4; ++mt) {
        const int row = 64 * wm + 16 * mt + l15;
        af[mt] = *(const bf16x8*)(as_ + row * 128 + ((64 * ki + 16 * l4) ^ ((row & 7) << 4)));
      }
#pragma unroll
      for (int nt = 0; nt < 4; ++nt) {
        const int row = 64 * wn + 16 * nt + l15;
        bq[nt] = *(const bf16x8*)(bs_ + row * 128 + ((64 * ki + 16 * l4) ^ ((row & 7) << 4)));
      }
#pragma unroll
      for (int mt = 0; mt < 4; ++mt)
#pragma unroll
        for (int nt = 0; nt < 4; ++nt)
          acc[mt][nt] = __builtin_amdgcn_mfma_f32_16x16x32_bf16(af[mt], bq[nt], acc[mt][nt], 0, 0, 0);
    }
    __syncthreads();
  }
#pragma unroll
  for (int nt = 0; nt < 4; ++nt) {
    const int col = bn * 128 + 64 * wn + 16 * nt + l15;
    const float bias = bproj[col];
#pragma unroll
    for (int mt = 0; mt < 4; ++mt) {
      const int r0 = bm * 128 + 64 * wm + 16 * mt + 4 * l4;
#pragma unroll
      for (int jj = 0; jj < 4; ++jj)
        out[(size_t)(r0 + jj) * 512 + col] = acc[mt][nt][jj] + bias;
    }
  }
}

// ---------------------------------------------------------------------------
extern "C" void kernel_launch(void* const* d_in, const int* in_sizes, int n_in,
                              void* d_out, int out_size, void* d_ws, size_t ws_size,
                              hipStream_t stream) {
  const float* x = (const float*)d_in[0];
  const float* wqkv = (const float*)d_in[1];
  const float* wproj = (const float*)d_in[2];
  const float* bproj = (const float*)d_in[3];
  const float* relk = (const float*)d_in[4];
  const float* relv = (const float*)d_in[5];
  float* out = (float*)d_out;

  char* ws = (char*)d_ws;
  const size_t MB = 1024 * 1024;
  // region A (64MB): x_t during qkv_gemm, then aout_t from attn onward
  short* xa_t = (short*)ws;
  short* vT_g = (short*)(ws + 64 * MB);                 // 64MB
  short* wq_t = (short*)(ws + 128 * MB);                // 1.5MB
  short* wp_t = (short*)(ws + 128 * MB + 1572864);      // 0.5MB
  short* relk_b = (short*)(ws + 128 * MB + 2097152);    // 32KB
  short* relvT_b = (short*)(ws + 128 * MB + 2129920);   // 32KB
  short* q_gg = (short*)d_out;                          // parked in d_out
  short* k_gg = (short*)((char*)d_out + 64 * MB);       // until proj overwrites

  prep_kernel<<<dim3(528), dim3(256), 0, stream>>>(wqkv, wproj, relk, relv, wq_t,
                                                   wp_t, relk_b, relvT_b);
  xconv_kernel<<<dim3(16384), dim3(256), 0, stream>>>(x, xa_t);
  qkv_gemm<<<dim3(6144), dim3(256), 0, stream>>>(xa_t, wq_t, q_gg, k_gg, vT_g);
  attn_kernel<<<dim3(8192), dim3(256), 0, stream>>>(q_gg, k_gg, vT_g, relk_b,
                                                    relvT_b, xa_t);
  proj_kernel<<<dim3(2048), dim3(256), 0, stream>>>(xa_t, wp_t, bproj, out);
}

// Round 5
// 376.057 us; speedup vs baseline: 1.6312x; 1.0255x over previous
//
#include <hip/hip_runtime.h>
#include <hip/hip_bf16.h>
#include <stdint.h>
#include <stddef.h>

typedef __attribute__((ext_vector_type(8))) short bf16x8;
typedef __attribute__((ext_vector_type(4))) float f32x4;

typedef __attribute__((address_space(1))) const unsigned int g_as1;
typedef __attribute__((address_space(3))) unsigned int lds_as3;
__device__ __forceinline__ void gload_lds16(const void* g, void* l) {
  __builtin_amdgcn_global_load_lds((g_as1*)g, (lds_as3*)l, 16, 0, 0);
}

__device__ __forceinline__ unsigned short f2bf(float f) {
  union { float f; unsigned int u; } v; v.f = f;
  unsigned int u = v.u;
  u += 0x7fffu + ((u >> 16) & 1u);   // round-to-nearest-even
  return (unsigned short)(u >> 16);
}
__device__ __forceinline__ float bf2f(unsigned short s) {
  union { unsigned int u; float f; } v; v.u = ((unsigned int)s) << 16;
  return v.f;
}
// packed f32x2 -> bf16x2 (RTNE) via vendor intrinsic; compiler emits the
// gfx950 HW op with correct hazard handling (hand asm NaN'd — round 4).
__device__ __forceinline__ unsigned cvt_pk_bf16(float lo, float hi) {
  __hip_bfloat162 h2 = __float22bfloat162_rn(make_float2(lo, hi));
  unsigned r;
  __builtin_memcpy(&r, &h2, 4);
  return r;
}

// Tile image layout: a (bm,kk) tile of 128 rows x 64 cols bf16 occupies 16KB;
// element (r,c) at byte  r*128 + ((c*2) ^ ((r&7)<<4)).  This equals the
// swizzled LDS image, so linear global_load_lds reproduces it in LDS.

// ---------------------------------------------------------------------------
// prep: wqkv -> tile image [bn=12][kk=8]; wproj -> tile image [bn=4][kk=8];
//       relk_b [256][64] plain (rows>=225 zero); relvT_b [64][256] plain.
// ---------------------------------------------------------------------------
__global__ void prep_kernel(const float* __restrict__ wqkv,
                            const float* __restrict__ wproj,
                            const float* __restrict__ relk,
                            const float* __restrict__ relv,
                            short* __restrict__ wq_t,
                            short* __restrict__ wp_t,
                            short* __restrict__ relk_b,
                            short* __restrict__ relvT_b) {
  const int g = blockIdx.x * 256 + threadIdx.x;  // 0..135167
  if (g < 98304) {  // wqkv: 1536 rows x 64 granules
    const int row = g >> 6, c8 = g & 63;
    const float* s = wqkv + (size_t)row * 512 + c8 * 8;
    float4 f0 = *(const float4*)s;
    float4 f1 = *(const float4*)(s + 4);
    uint4 w;
    w.x = f2bf(f0.x) | ((unsigned)f2bf(f0.y) << 16);
    w.y = f2bf(f0.z) | ((unsigned)f2bf(f0.w) << 16);
    w.z = f2bf(f1.x) | ((unsigned)f2bf(f1.y) << 16);
    w.w = f2bf(f1.z) | ((unsigned)f2bf(f1.w) << 16);
    const int bn = row >> 7, rl = row & 127, kk = c8 >> 3, c8l = c8 & 7;
    char* d = (char*)wq_t + (size_t)(bn * 8 + kk) * 16384 + rl * 128 +
              ((c8l * 16) ^ ((rl & 7) << 4));
    *(uint4*)d = w;
  } else if (g < 131072) {  // wproj: 512 rows x 64 granules
    const int g2 = g - 98304;
    const int row = g2 >> 6, c8 = g2 & 63;
    const float* s = wproj + (size_t)row * 512 + c8 * 8;
    float4 f0 = *(const float4*)s;
    float4 f1 = *(const float4*)(s + 4);
    uint4 w;
    w.x = f2bf(f0.x) | ((unsigned)f2bf(f0.y) << 16);
    w.y = f2bf(f0.z) | ((unsigned)f2bf(f0.w) << 16);
    w.z = f2bf(f1.x) | ((unsigned)f2bf(f1.y) << 16);
    w.w = f2bf(f1.z) | ((unsigned)f2bf(f1.w) << 16);
    const int bn = row >> 7, rl = row & 127, kk = c8 >> 3, c8l = c8 & 7;
    char* d = (char*)wp_t + (size_t)(bn * 8 + kk) * 16384 + rl * 128 +
              ((c8l * 16) ^ ((rl & 7) << 4));
    *(uint4*)d = w;
  } else if (g < 133120) {  // relk: 256 rows x 8 granules
    const int g3 = g - 131072;
    const int nb = g3 >> 3, c8 = g3 & 7;
    uint4 w = {0u, 0u, 0u, 0u};
    if (nb < 225) {
      const float* s = relk + (size_t)nb * 64 + c8 * 8;
      float4 f0 = *(const float4*)s;
      float4 f1 = *(const float4*)(s + 4);
      w.x = f2bf(f0.x) | ((unsigned)f2bf(f0.y) << 16);
      w.y = f2bf(f0.z) | ((unsigned)f2bf(f0.w) << 16);
      w.z = f2bf(f1.x) | ((unsigned)f2bf(f1.y) << 16);
      w.w = f2bf(f1.z) | ((unsigned)f2bf(f1.w) << 16);
    }
    *(uint4*)(relk_b + nb * 64 + c8 * 8) = w;
  } else {  // relvT: 64 d-rows x 32 granules of 8
    const int g4 = g - 133120;
    const int d = g4 >> 5, nb0 = (g4 & 31) * 8;
    unsigned short s[8];
#pragma unroll
    for (int j = 0; j < 8; ++j) {
      const int nb = nb0 + j;
      s[j] = (nb < 225) ? f2bf(relv[(size_t)nb * 64 + d]) : (unsigned short)0;
    }
    uint4 w;
    w.x = s[0] | ((unsigned)s[1] << 16);
    w.y = s[2] | ((unsigned)s[3] << 16);
    w.z = s[4] | ((unsigned)s[5] << 16);
    w.w = s[6] | ((unsigned)s[7] << 16);
    *(uint4*)(relvT_b + d * 256 + nb0) = w;
  }
}

// ---------------------------------------------------------------------------
// xconv: x fp32 [65536][512] -> bf16 tile image [bm=512][kk=8].
// ---------------------------------------------------------------------------
__global__ void xconv_kernel(const float* __restrict__ x, short* __restrict__ x_t) {
  const int g = blockIdx.x * 256 + threadIdx.x;  // 0..4194303
  const int row = g >> 6, c8 = g & 63;
  const float* s = x + (size_t)row * 512 + c8 * 8;
  float4 f0 = *(const float4*)s;
  float4 f1 = *(const float4*)(s + 4);
  uint4 w;
  w.x = f2bf(f0.x) | ((unsigned)f2bf(f0.y) << 16);
  w.y = f2bf(f0.z) | ((unsigned)f2bf(f0.w) << 16);
  w.z = f2bf(f1.x) | ((unsigned)f2bf(f1.y) << 16);
  w.w = f2bf(f1.z) | ((unsigned)f2bf(f1.w) << 16);
  const int bm = row >> 7, rl = row & 127, kk = c8 >> 3, c8l = c8 & 7;
  char* d = (char*)x_t + (size_t)(bm * 8 + kk) * 16384 + rl * 128 +
            ((c8l * 16) ^ ((rl & 7) << 4));
  *(uint4*)d = w;
}

// ---------------------------------------------------------------------------
// QKV GEMM (m97 structure): M=65536, N=1536, K=512. A,B pre-tiled bf16.
// ---------------------------------------------------------------------------
__global__ __launch_bounds__(256)
void qkv_gemm(const short* __restrict__ x_t, const short* __restrict__ wq_t,
              short* __restrict__ q_g, short* __restrict__ k_g,
              short* __restrict__ vT_g) {
  __shared__ __align__(16) short As[8192];  // 16KB
  __shared__ __align__(16) short Bs[8192];  // 16KB
  const int tid = threadIdx.x;
  const int lane = tid & 63;
  const int l15 = lane & 15, l4 = lane >> 4;
  const int wave = tid >> 6;
  const int wm = wave >> 1, wn = wave & 1;
  const int bid = blockIdx.x;  // 6144
  const int wg = (bid & 7) * 768 + (bid >> 3);
  const int bn = wg % 12;
  const int bm = wg / 12;
  char* as_ = (char*)As;
  char* bs_ = (char*)Bs;
  const char* abase = (const char*)x_t + (size_t)bm * 131072;
  const char* bbase = (const char*)wq_t + (size_t)bn * 131072;
  const int soff = tid * 16;

  const f32x4 fz = {0.f, 0.f, 0.f, 0.f};
  f32x4 acc[4][4];
#pragma unroll
  for (int mt = 0; mt < 4; ++mt)
#pragma unroll
    for (int nt = 0; nt < 4; ++nt) acc[mt][nt] = fz;

#pragma unroll 1
  for (int kk = 0; kk < 8; ++kk) {
    const char* ga = abase + kk * 16384 + soff;
    const char* gb = bbase + kk * 16384 + soff;
#pragma unroll
    for (int i = 0; i < 4; ++i) {
      gload_lds16(ga + i * 4096, as_ + soff + i * 4096);
      gload_lds16(gb + i * 4096, bs_ + soff + i * 4096);
    }
    __syncthreads();
#pragma unroll
    for (int ki = 0; ki < 2; ++ki) {
      bf16x8 af[4], bfr[4];
#pragma unroll
      for (int mt = 0; mt < 4; ++mt) {
        const int row = 64 * wm + 16 * mt + l15;
        af[mt] = *(const bf16x8*)(as_ + row * 128 + ((64 * ki + 16 * l4) ^ ((row & 7) << 4)));
      }
#pragma unroll
      for (int nt = 0; nt < 4; ++nt) {
        const int row = 64 * wn + 16 * nt + l15;
        bfr[nt] = *(const bf16x8*)(bs_ + row * 128 + ((64 * ki + 16 * l4) ^ ((row & 7) << 4)));
      }
#pragma unroll
      for (int mt = 0; mt < 4; ++mt)
#pragma unroll
        for (int nt = 0; nt < 4; ++nt)
          acc[mt][nt] = __builtin_amdgcn_mfma_f32_16x16x32_bf16(af[mt], bfr[nt], acc[mt][nt], 0, 0, 0);
    }
    __syncthreads();
  }

  const int three = bn >> 2;  // 0=q 1=k 2=v
  if (three < 2) {
    short* dst = (three == 0) ? q_g : k_g;
#pragma unroll
    for (int mt = 0; mt < 4; ++mt) {
      const int m0 = bm * 128 + 64 * wm + 16 * mt + 4 * l4;
      const int b = m0 >> 6, t0 = m0 & 63;
#pragma unroll
      for (int nt = 0; nt < 4; ++nt) {
        const int n = bn * 128 + 64 * wn + 16 * nt + l15;
        const int h = (n >> 6) & 7, d = n & 63;
        short* p = dst + (size_t)(b * 8 + h) * 4096 + d;
#pragma unroll
        for (int jj = 0; jj < 4; ++jj)
          p[(t0 + jj) * 64] = (short)f2bf(acc[mt][nt][jj]);
      }
    }
  } else {
#pragma unroll
    for (int mt = 0; mt < 4; ++mt) {
      const int m0 = bm * 128 + 64 * wm + 16 * mt + 4 * l4;
      const int b = m0 >> 6, t0 = m0 & 63;
#pragma unroll
      for (int nt = 0; nt < 4; ++nt) {
        const int n = bn * 128 + 64 * wn + 16 * nt + l15;
        const int h = (n >> 6) & 7, d = n & 63;
        uint2 w;
        w.x = cvt_pk_bf16(acc[mt][nt][0], acc[mt][nt][1]);
        w.y = cvt_pk_bf16(acc[mt][nt][2], acc[mt][nt][3]);
        *(uint2*)(vT_g + (size_t)((b * 8 + h) * 64 + d) * 64 + t0) = w;
      }
    }
  }
}

// ---------------------------------------------------------------------------
// attention: one block per (b,h), 4 waves; wave w owns rows [16w,16w+16).
// VALU-lean: packed bf16 converts, algebraic nb (= Cj - disp_i), folded scale.
// ---------------------------------------------------------------------------
__global__ __launch_bounds__(256, 4)
void attn_kernel(const short* __restrict__ q_g, const short* __restrict__ k_g,
                 const short* __restrict__ vT_g, const short* __restrict__ relk,
                 const short* __restrict__ relvT, short* __restrict__ aout_t) {
  __shared__ __align__(16) short srel_s[64 * 256];  // 32KB swizzled [i][nb]; reused as P
  __shared__ __align__(16) short attn_s[64 * 64];   // 8KB swizzled  [i][j]
  const int tid = threadIdx.x, lane = tid & 63, w = tid >> 6;
  const int l15 = lane & 15, l4 = lane >> 4;
  const int bh = blockIdx.x;
  const short* qb = q_g + (size_t)bh * 4096;
  const short* kb = k_g + (size_t)bh * 4096;
  const short* vb = vT_g + (size_t)bh * 4096;
  char* ss = (char*)srel_s;
  char* as = (char*)attn_s;
  const f32x4 fz = {0.f, 0.f, 0.f, 0.f};

  // ---- Srel^T: D[nb,i] = sum_d relk[nb,d] q[i,d]
  bf16x8 bq[4][2];
#pragma unroll
  for (int nt = 0; nt < 4; ++nt)
#pragma unroll
    for (int kkk = 0; kkk < 2; ++kkk)
      bq[nt][kkk] = *(const bf16x8*)(qb + (16 * nt + l15) * 64 + 32 * kkk + 8 * l4);
#pragma unroll
  for (int mtl = 0; mtl < 4; ++mtl) {
    const int mt = 4 * w + mtl;
    bf16x8 ar0 = *(const bf16x8*)(relk + (16 * mt + l15) * 64 + 8 * l4);
    bf16x8 ar1 = *(const bf16x8*)(relk + (16 * mt + l15) * 64 + 32 + 8 * l4);
#pragma unroll
    for (int nt = 0; nt < 4; ++nt) {
      f32x4 a = fz;
      a = __builtin_amdgcn_mfma_f32_16x16x32_bf16(ar0, bq[nt][0], a, 0, 0, 0);
      a = __builtin_amdgcn_mfma_f32_16x16x32_bf16(ar1, bq[nt][1], a, 0, 0, 0);
      const int i = 16 * nt + l15;
      const int nb0 = 16 * mt + 4 * l4;
      uint2 wv;
      wv.x = cvt_pk_bf16(a[0], a[1]);
      wv.y = cvt_pk_bf16(a[2], a[3]);
      *(uint2*)(ss + i * 512 + ((nb0 * 2) ^ ((i & 7) << 4))) = wv;
    }
  }

  // ---- S^T (own strip): D[j,i] = sum_d k[j,d] q[i,d], i = 16w+l15
  f32x4 sacc[4];
#pragma unroll
  for (int jt = 0; jt < 4; ++jt) {
    sacc[jt] = fz;
    bf16x8 ak0 = *(const bf16x8*)(kb + (16 * jt + l15) * 64 + 8 * l4);
    bf16x8 ak1 = *(const bf16x8*)(kb + (16 * jt + l15) * 64 + 32 + 8 * l4);
    sacc[jt] = __builtin_amdgcn_mfma_f32_16x16x32_bf16(ak0, bq[w][0], sacc[jt], 0, 0, 0);
    sacc[jt] = __builtin_amdgcn_mfma_f32_16x16x32_bf16(ak1, bq[w][1], sacc[jt], 0, 0, 0);
  }
  __syncthreads();  // barrier 1: Srel complete

  // ---- softmax over own rows (4 lanes per row, 16 logits each) ----
  // nb(i,j) = [15*(j>>3)+(j&7)+112] - [15*(i>>3)+(i&7)].  For this lane's
  // j = 16jt+4l4+rg:  nb*2 = (60jt+2rg) + off2,  off2 per-thread constant.
  const int i = 16 * w + l15;
  const int swz = (i & 7) << 4;
  const int ibase = i * 512;
  const int off2 = 2 * (15 * (l4 >> 1) + 4 * (l4 & 1) + 112 - (15 * (i >> 3) + (i & 7)));
  float p[16];
  float mx = -1e30f;
#pragma unroll
  for (int jt = 0; jt < 4; ++jt)
#pragma unroll
    for (int rg = 0; rg < 4; ++rg) {
      const int adr = ibase + (((60 * jt + 2 * rg) + off2) ^ swz);
      const float sr = bf2f(*(const unsigned short*)(ss + adr));
      const float lv = sacc[jt][rg] + sr;
      p[4 * jt + rg] = lv;
      mx = fmaxf(mx, lv);
    }
  mx = fmaxf(mx, __shfl_xor(mx, 16));
  mx = fmaxf(mx, __shfl_xor(mx, 32));
  float sum = 0.f;
#pragma unroll
  for (int q2 = 0; q2 < 16; ++q2) {
    p[q2] = __expf((p[q2] - mx) * 0.125f);
    sum += p[q2];
  }
  sum += __shfl_xor(sum, 16);
  sum += __shfl_xor(sum, 32);
  const float rs = 1.0f / sum;
  unsigned pk[8];
#pragma unroll
  for (int h2 = 0; h2 < 8; ++h2)
    pk[h2] = cvt_pk_bf16(p[2 * h2] * rs, p[2 * h2 + 1] * rs);
  // attn_s[i][j] packed
#pragma unroll
  for (int jt = 0; jt < 4; ++jt) {
    uint2 wv;
    wv.x = pk[2 * jt];
    wv.y = pk[2 * jt + 1];
    *(uint2*)(as + i * 128 + (((16 * jt + 4 * l4) * 2) ^ swz)) = wv;
  }
  {  // zero own P row quarter (reuse Srel buffer; wave-order makes this safe)
    const uint4 uz = {0u, 0u, 0u, 0u};
#pragma unroll
    for (int c = 0; c < 8; ++c)
      *(uint4*)(ss + ibase + ((l4 * 128 + c * 16) ^ swz)) = uz;
  }
#pragma unroll
  for (int jt = 0; jt < 4; ++jt)  // scatter P (injective per row)
#pragma unroll
    for (int rg = 0; rg < 4; ++rg) {
      const int adr = ibase + (((60 * jt + 2 * rg) + off2) ^ swz);
      const int q2 = 4 * jt + rg;
      const unsigned v = pk[q2 >> 1] >> ((q2 & 1) * 16);
      *(unsigned short*)(ss + adr) = (unsigned short)v;
    }
  __syncthreads();  // barrier 2

  // ---- PV: D[d,t] = sum_j vT[d,j]attn[t,j] + sum_nb relvT[d,nb]P[t,nb]
  f32x4 oacc[4];
#pragma unroll
  for (int nt = 0; nt < 4; ++nt) oacc[nt] = fz;
#pragma unroll
  for (int kkk = 0; kkk < 2; ++kkk) {
    bf16x8 av = *(const bf16x8*)(vb + (16 * w + l15) * 64 + 32 * kkk + 8 * l4);
#pragma unroll
    for (int nt = 0; nt < 4; ++nt) {
      const int t = 16 * nt + l15;
      bf16x8 bp = *(const bf16x8*)(as + t * 128 + (((32 * kkk + 8 * l4) * 2) ^ ((t & 7) << 4)));
      oacc[nt] = __builtin_amdgcn_mfma_f32_16x16x32_bf16(av, bp, oacc[nt], 0, 0, 0);
    }
  }
#pragma unroll
  for (int kkk = 0; kkk < 8; ++kkk) {
    bf16x8 arv = *(const bf16x8*)(relvT + (16 * w + l15) * 256 + 32 * kkk + 8 * l4);
#pragma unroll
    for (int nt = 0; nt < 4; ++nt) {
      const int t = 16 * nt + l15;
      bf16x8 bp = *(const bf16x8*)(ss + t * 512 + (((32 * kkk + 8 * l4) * 2) ^ ((t & 7) << 4)));
      oacc[nt] = __builtin_amdgcn_mfma_f32_16x16x32_bf16(arv, bp, oacc[nt], 0, 0, 0);
    }
  }
  // epilogue: write into proj tile image. global row m = b*64+t; tile bm=m>>7,
  // kk = h; in-tile r = (b&1)*64 + t, c = d.
  const int b = bh >> 3, h = bh & 7;
  char* abase = (char*)aout_t + (size_t)((b >> 1) * 8 + h) * 16384;
  const int rbase = (b & 1) * 64;
#pragma unroll
  for (int nt = 0; nt < 4; ++nt) {
    const int t = 16 * nt + l15;
    const int r = rbase + t;
    const int d0 = 16 * w + 4 * l4;
    uint2 wv;
    wv.x = cvt_pk_bf16(oacc[nt][0], oacc[nt][1]);
    wv.y = cvt_pk_bf16(oacc[nt][2], oacc[nt][3]);
    *(uint2*)(abase + r * 128 + ((d0 * 2) ^ ((r & 7) << 4))) = wv;
  }
}

// ---------------------------------------------------------------------------
// proj (m97 structure): out = aout(bf16,tiled) @ wproj^T(tiled) + b_proj.
// ---------------------------------------------------------------------------
__global__ __launch_bounds__(256)
void proj_kernel(const short* __restrict__ a_t, const short* __restrict__ wp_t,
                 const float* __restrict__ bproj, float* __restrict__ out) {
  __shared__ __align__(16) short As[8192];
  __shared__ __align__(16) short Bs[8192];
  const int tid = threadIdx.x;
  const int lane = tid & 63;
  const int wave = tid >> 6;
  const int wm = wave >> 1, wn = wave & 1;
  const int l15 = lane & 15, l4 = lane >> 4;
  const int bid = blockIdx.x;  // 2048
  const int wg = (bid & 7) * 256 + (bid >> 3);
  const int bn = wg & 3;
  const int bm = wg >> 2;
  char* as_ = (char*)As;
  char* bs_ = (char*)Bs;
  const char* abase = (const char*)a_t + (size_t)bm * 131072;
  const char* bbase = (const char*)wp_t + (size_t)bn * 131072;
  const int soff = tid * 16;

  const f32x4 fz = {0.f, 0.f, 0.f, 0.f};
  f32x4 acc[4][4];
#pragma unroll
  for (int mt = 0; mt < 4; ++mt)
#pragma unroll
    for (int nt = 0; nt < 4; ++nt) acc[mt][nt] = fz;

#pragma unroll 1
  for (int kk = 0; kk < 8; ++kk) {
    const char* ga = abase + kk * 16384 + soff;
    const char* gb = bbase + kk * 16384 + soff;
#pragma unroll
    for (int i = 0; i < 4; ++i) {
      gload_lds16(ga + i * 4096, as_ + soff + i * 4096);
      gload_lds16(gb + i * 4096, bs_ + soff + i * 4096);
    }
    __syncthreads();
#pragma unroll
    for (int ki = 0; ki < 2; ++ki) {
      bf16x8 af[4], bq[4];
#pragma unroll
      for (int mt = 0; mt < 4; ++mt) {
        const int row = 64 * wm + 16 * mt + l15;
        af[mt] = *(const bf16x8*)(as_ + row * 128 + ((64 * ki + 16 * l4) ^ ((row & 7) << 4)));
      }
#pragma unroll
      for (int nt = 0; nt < 4; ++nt) {
        const int row = 64 * wn + 16 * nt + l15;
        bq[nt] = *(const bf16x8*)(bs_ + row * 128 + ((64 * ki + 16 * l4) ^ ((row & 7) << 4)));
      }
#pragma unroll
      for (int mt = 0; mt < 4; ++mt)
#pragma unroll
        for (int nt = 0; nt < 4; ++nt)
          acc[mt][nt] = __builtin_amdgcn_mfma_f32_16x16x32_bf16(af[mt], bq[nt], acc[mt][nt], 0, 0, 0);
    }
    __syncthreads();
  }
#pragma unroll
  for (int nt = 0; nt < 4; ++nt) {
    const int col = bn * 128 + 64 * wn + 16 * nt + l15;
    const float bias = bproj[col];
#pragma unroll
    for (int mt = 0; mt < 4; ++mt) {
      const int r0 = bm * 128 + 64 * wm + 16 * mt + 4 * l4;
#pragma unroll
      for (int jj = 0; jj < 4; ++jj)
        out[(size_t)(r0 + jj) * 512 + col] = acc[mt][nt][jj] + bias;
    }
  }
}

// ---------------------------------------------------------------------------
extern "C" void kernel_launch(void* const* d_in, const int* in_sizes, int n_in,
                              void* d_out, int out_size, void* d_ws, size_t ws_size,
                              hipStream_t stream) {
  const float* x = (const float*)d_in[0];
  const float* wqkv = (const float*)d_in[1];
  const float* wproj = (const float*)d_in[2];
  const float* bproj = (const float*)d_in[3];
  const float* relk = (const float*)d_in[4];
  const float* relv = (const float*)d_in[5];
  float* out = (float*)d_out;

  char* ws = (char*)d_ws;
  const size_t MB = 1024 * 1024;
  // region A (64MB): x_t during qkv_gemm, then aout_t from attn onward
  short* xa_t = (short*)ws;
  short* vT_g = (short*)(ws + 64 * MB);                 // 64MB
  short* wq_t = (short*)(ws + 128 * MB);                // 1.5MB
  short* wp_t = (short*)(ws + 128 * MB + 1572864);      // 0.5MB
  short* relk_b = (short*)(ws + 128 * MB + 2097152);    // 32KB
  short* relvT_b = (short*)(ws + 128 * MB + 2129920);   // 32KB
  short* q_gg = (short*)d_out;                          // parked in d_out
  short* k_gg = (short*)((char*)d_out + 64 * MB);       // until proj overwrites

  prep_kernel<<<dim3(528), dim3(256), 0, stream>>>(wqkv, wproj, relk, relv, wq_t,
                                                   wp_t, relk_b, relvT_b);
  xconv_kernel<<<dim3(16384), dim3(256), 0, stream>>>(x, xa_t);
  qkv_gemm<<<dim3(6144), dim3(256), 0, stream>>>(xa_t, wq_t, q_gg, k_gg, vT_g);
  attn_kernel<<<dim3(8192), dim3(256), 0, stream>>>(q_gg, k_gg, vT_g, relk_b,
                                                    relvT_b, xa_t);
  proj_kernel<<<dim3(2048), dim3(256), 0, stream>>>(xa_t, wp_t, bproj, out);
}